// Round 4
// baseline (1052.508 us; speedup 1.0000x reference)
//
#include <hip/hip_runtime.h>
#include <hip/hip_bf16.h>
#include <stdint.h>

#define NN 40000
#define EE 640000
#define GG 256
#define FFE 9
#define HH 128

typedef __bf16 bf16;
typedef __bf16 bf16x8 __attribute__((ext_vector_type(8)));
typedef float f32x4 __attribute__((ext_vector_type(4)));

__device__ __forceinline__ f32x4 mfma16(bf16x8 a, bf16x8 b, f32x4 c){
  return __builtin_amdgcn_mfma_f32_16x16x32_bf16(a, b, c, 0, 0, 0);
}
__device__ __forceinline__ float silu_f(float x){
  return x * __builtin_amdgcn_rcpf(1.0f + __expf(-x));
}
// byte-offset XOR swizzle for [row][256B] LDS tiles
__device__ __forceinline__ int swz(int row, int cb){
  return row*256 + (cb ^ ((row & 7) << 4));
}

// ---------------- merged prep: weight transposes + bcat + cnt zero + embedding ----------------
__global__ __launch_bounds__(256) void k_prep(
    const float* __restrict__ edge_w1, const float* __restrict__ edge_w2,
    const float* __restrict__ node_w1, const float* __restrict__ node_w2,
    const float* __restrict__ edge_b1,
    const float* __restrict__ x, const float* __restrict__ emb_w,
    const float* __restrict__ emb_b,
    bf16* __restrict__ wcatT, bf16* __restrict__ w2T,
    bf16* __restrict__ nw1T, bf16* __restrict__ nw2T,
    float* __restrict__ bcat, float* __restrict__ h, bf16* __restrict__ h_bf,
    int* __restrict__ cnt)
{
  int b = blockIdx.x, tid = threadIdx.x;
  if (b < 192){                 // wcat part A: [n][k] <- edge_w1 rows 0..127
    int l = b/64; int t2 = (b%64)*256 + tid;
    int n = t2 >> 7, k = t2 & 127;
    wcatT[(size_t)l*32768 + n*128 + k] = (bf16)edge_w1[(size_t)l*32896 + k*128 + n];
  } else if (b < 384){          // wcat part B: edge_w1 rows 128..255
    int lb = b - 192; int l = lb/64; int t2 = (lb%64)*256 + tid;
    int n = t2 >> 7, k = t2 & 127;
    wcatT[(size_t)l*32768 + 16384 + n*128 + k] = (bf16)edge_w1[(size_t)l*32896 + (128+k)*128 + n];
  } else if (b < 576){          // w2T
    int lb = b - 384; int l = lb/64; int t2 = (lb%64)*256 + tid;
    int n = t2 >> 7, k = t2 & 127;
    w2T[(size_t)l*16384 + n*128 + k] = (bf16)edge_w2[(size_t)l*16384 + k*128 + n];
  } else if (b < 960){          // nw1T [128][256]
    int lb = b - 576; int l = lb/128; int t2 = (lb%128)*256 + tid;
    int n = t2 >> 8, k = t2 & 255;
    nw1T[(size_t)l*32768 + n*256 + k] = (bf16)node_w1[(size_t)l*32768 + k*128 + n];
  } else if (b < 1152){         // nw2T
    int lb = b - 960; int l = lb/64; int t2 = (lb%64)*256 + tid;
    int n = t2 >> 7, k = t2 & 127;
    nw2T[(size_t)l*16384 + n*128 + k] = (bf16)node_w2[(size_t)l*16384 + k*128 + n];
  } else if (b < 1155){         // bcat
    int l = b - 1152;
    bcat[l*256 + tid] = (tid < 128) ? edge_b1[l*128 + tid] : 0.0f;
  } else if (b < 1312){         // cnt zero
    int i = (b - 1155)*256 + tid;
    if (i < NN) cnt[i] = 0;
  } else {                      // embedding: 20000 blocks
    int idx = (b - 1312)*256 + tid;
    int n = idx >> 7, f = idx & 127;
    float s = emb_b[f];
    const float* xr = x + n*FFE;
    #pragma unroll
    for (int k=0;k<FFE;++k) s += xr[k]*emb_w[k*HH + f];
    h[idx] = s;
    h_bf[idx] = (bf16)s;
  }
}

// ---------------- counting sort by dst ----------------
__global__ __launch_bounds__(256) void k_hist(const int* __restrict__ dst, int* __restrict__ cnt){
  int e = blockIdx.x*256 + threadIdx.x;
  if (e < EE) atomicAdd(&cnt[dst[e]], 1);
}

__global__ __launch_bounds__(1024) void k_scan(const int* __restrict__ cnt, int* __restrict__ cursor, int n){
  __shared__ int s_wsum[16];
  __shared__ int s_run;
  int tid = threadIdx.x, lane = tid & 63, wv = tid >> 6;
  if (tid == 0) s_run = 0;
  __syncthreads();
  for (int base=0; base<n; base+=4096){
    int i = base + tid*4;
    int c0 = (i  <n)? cnt[i  ] : 0;
    int c1 = (i+1<n)? cnt[i+1] : 0;
    int c2 = (i+2<n)? cnt[i+2] : 0;
    int c3 = (i+3<n)? cnt[i+3] : 0;
    int t0 = c0, t1 = t0+c1, t2 = t1+c2, t3 = t2+c3;
    int xx = t3;
    #pragma unroll
    for (int off=1; off<64; off<<=1){ int t = __shfl_up(xx, off); if (lane>=off) xx += t; }
    if (lane==63) s_wsum[wv] = xx;
    __syncthreads();
    if (wv==0 && lane<16){
      int y = s_wsum[lane];
      #pragma unroll
      for (int off=1; off<16; off<<=1){ int t = __shfl_up(y, off, 16); if (lane>=off) y += t; }
      s_wsum[lane] = y;
    }
    __syncthreads();
    int woff = wv ? s_wsum[wv-1] : 0;
    int run = s_run;
    int eb = run + woff + xx - t3;
    if (i  <n) cursor[i  ] = eb;
    if (i+1<n) cursor[i+1] = eb + t0;
    if (i+2<n) cursor[i+2] = eb + t1;
    if (i+3<n) cursor[i+3] = eb + t2;
    __syncthreads();
    if (tid==0) s_run = run + s_wsum[15];
    __syncthreads();
  }
}

__global__ __launch_bounds__(256) void k_scatter(
    const int* __restrict__ ei, const float* __restrict__ pos,
    int* __restrict__ cursor, int4* __restrict__ rec)
{
  int e = blockIdx.x*256 + threadIdx.x;
  if (e >= EE) return;
  int s = ei[e], d = ei[EE + e];
  int p = atomicAdd(&cursor[d], 1);
  float dx = pos[d*3+0]-pos[s*3+0];
  float dy = pos[d*3+1]-pos[s*3+1];
  float dz = pos[d*3+2]-pos[s*3+2];
  int4 rc; rc.x = s; rc.y = d; rc.z = __float_as_int(sqrtf(dx*dx+dy*dy+dz*dz)); rc.w = 0;
  rec[p] = rc;
}

// ---------------- 128x64-tile bf16 MFMA GEMM ----------------
template<int KTOT, int K1, int ACT, bool A1BF, bool BIAS, bool RESID, bool OBF, bool OF, bool ZAGGR>
__global__ __launch_bounds__(256) void k_gemm(
    const void* __restrict__ a1v, const float* __restrict__ a2,
    const bf16* __restrict__ wt, const float* __restrict__ bias,
    const float* __restrict__ resid, bf16* __restrict__ outb,
    float* __restrict__ outf, int Nw, float* __restrict__ aggr)
{
  constexpr int LDK = 136;
  __shared__ bf16 s_a[128*LDK];
  __shared__ bf16 s_w[64*LDK];
  int tid = threadIdx.x, lane = tid & 63, w = tid >> 6;
  int m0 = blockIdx.x*128, n0 = blockIdx.y*64;
  if (ZAGGR && blockIdx.y == 0){
    int nrows = NN - m0; if (nrows > 128) nrows = 128;
    f32x4 z = {0.f,0.f,0.f,0.f};
    for (int i = tid; i < nrows*32; i += 256)
      *(f32x4*)(aggr + (size_t)m0*128 + (size_t)i*4) = z;
  }
  f32x4 acc[2][4];
  #pragma unroll
  for (int i=0;i<2;++i)
    #pragma unroll
    for (int j=0;j<4;++j)
      #pragma unroll
      for (int r=0;r<4;++r) acc[i][j][r]=0.f;
  int rsel = lane & 15, ksel = (lane>>4)*8;
  int wm = w*32;

  for (int kh=0; kh<KTOT; kh+=128){
    #pragma unroll
    for (int it=0; it<8; ++it){
      int idx = tid + it*256;
      int row = idx >> 4, col = (idx & 15)*8;
      int gc = kh + col;
      int grow = m0 + row; if (grow > NN-1) grow = NN-1;
      bf16x8 vv;
      if (gc < K1){
        if (A1BF){
          vv = *(const bf16x8*)((const bf16*)a1v + (size_t)grow*K1 + gc);
        } else {
          const float* srcp = (const float*)a1v + (size_t)grow*K1 + gc;
          f32x4 u0 = *(const f32x4*)srcp;
          f32x4 u1 = *(const f32x4*)(srcp+4);
          vv[0]=(bf16)u0[0]; vv[1]=(bf16)u0[1]; vv[2]=(bf16)u0[2]; vv[3]=(bf16)u0[3];
          vv[4]=(bf16)u1[0]; vv[5]=(bf16)u1[1]; vv[6]=(bf16)u1[2]; vv[7]=(bf16)u1[3];
        }
      } else {
        const float* srcp = a2 + (size_t)grow*(KTOT-K1) + (gc-K1);
        f32x4 u0 = *(const f32x4*)srcp;
        f32x4 u1 = *(const f32x4*)(srcp+4);
        vv[0]=(bf16)u0[0]; vv[1]=(bf16)u0[1]; vv[2]=(bf16)u0[2]; vv[3]=(bf16)u0[3];
        vv[4]=(bf16)u1[0]; vv[5]=(bf16)u1[1]; vv[6]=(bf16)u1[2]; vv[7]=(bf16)u1[3];
      }
      *(bf16x8*)&s_a[row*LDK + col] = vv;
    }
    #pragma unroll
    for (int it=0; it<4; ++it){
      int idx = tid + it*256;
      int row = idx >> 4, col = (idx & 15)*8;
      *(bf16x8*)&s_w[row*LDK + col] = *(const bf16x8*)(wt + (size_t)(n0+row)*KTOT + kh + col);
    }
    __syncthreads();
    #pragma unroll
    for (int ks=0; ks<4; ++ks){
      int kb = ks*32 + ksel;
      bf16x8 fa0 = *(const bf16x8*)&s_a[(wm+rsel)*LDK + kb];
      bf16x8 fa1 = *(const bf16x8*)&s_a[(wm+16+rsel)*LDK + kb];
      #pragma unroll
      for (int j=0;j<4;++j){
        bf16x8 fb = *(const bf16x8*)&s_w[(j*16+rsel)*LDK + kb];
        acc[0][j]=mfma16(fa0,fb,acc[0][j]);
        acc[1][j]=mfma16(fa1,fb,acc[1][j]);
      }
    }
    __syncthreads();
  }

  #pragma unroll
  for (int i=0;i<2;++i){
    #pragma unroll
    for (int j=0;j<4;++j){
      int col = n0 + j*16 + rsel;
      float bv = BIAS ? bias[col] : 0.0f;
      #pragma unroll
      for (int r=0;r<4;++r){
        int row = m0 + wm + i*16 + 4*(lane>>4) + r;
        if (row < NN){
          float v = acc[i][j][r] + bv;
          if (ACT==1) v = silu_f(v);
          if (RESID) v += resid[(size_t)row*Nw + col];
          if (OBF) outb[(size_t)row*Nw + col] = (bf16)v;
          if (OF)  outf[(size_t)row*Nw + col] = v;
        }
      }
    }
  }
}

// ---------------- fused edge MLP + segmented aggregation (v3) ----------------
// 128 edges/block, 512 threads, 32.5KB LDS; w2 read from global (L1-hot);
// m2 stored bf16 aliased on m1 buffer; store-vs-atomic run walk.
__global__ __launch_bounds__(512, 6) void k_edge(
    const bf16* __restrict__ P, const bf16* __restrict__ w2t,
    const float* __restrict__ w1r, const float* __restrict__ b2,
    const int4* __restrict__ rec, float* __restrict__ aggr)
{
  __shared__ char smem[32768];   // m1 bf16 [128][256B] swizzled; then m2 bf16 [128][256B] rotated
  __shared__ int s_dst[128];
  int tid = threadIdx.x, lane = tid & 63, w = tid >> 6;
  int bid = blockIdx.x;
  int swb = (bid & 7) * (EE/128/8) + (bid >> 3);   // XCD-chunked, 5000%8==0
  int e0 = swb * 128;

  // m1 = silu(PA[dst] + PB[src] + dist*w1r)  (b1 folded into P bias)
  int cq = (tid & 15)*8;
  int er = tid >> 4;           // 0..31
  int4 rc[4];
  #pragma unroll
  for (int it=0; it<4; ++it) rc[it] = rec[e0 + er + it*32];
  uint4 pau[4], pbu[4];
  #pragma unroll
  for (int it=0; it<4; ++it){
    pau[it] = *(const uint4*)(P + ((size_t)rc[it].y << 8) + cq);
    pbu[it] = *(const uint4*)(P + ((size_t)rc[it].x << 8) + 128 + cq);
  }
  if (cq == 0){
    #pragma unroll
    for (int it=0; it<4; ++it) s_dst[er + it*32] = rc[it].y;
  }
  f32x4 wr0 = *(const f32x4*)(w1r + cq);
  f32x4 wr1 = *(const f32x4*)(w1r + cq + 4);
  #pragma unroll
  for (int it=0; it<4; ++it){
    float dist = __int_as_float(rc[it].z);
    bf16x8 mm;
    #pragma unroll
    for (int j=0;j<4;++j){
      unsigned ua = (j<2)? ((const unsigned*)&pau[it])[j] : ((const unsigned*)&pau[it])[j];
      unsigned ub = ((const unsigned*)&pbu[it])[j];
      float al = __uint_as_float(ua << 16);
      float ah = __uint_as_float(ua & 0xFFFF0000u);
      float bl = __uint_as_float(ub << 16);
      float bh = __uint_as_float(ub & 0xFFFF0000u);
      float wlo = (j<2) ? wr0[2*j]   : wr1[2*(j-2)];
      float whi = (j<2) ? wr0[2*j+1] : wr1[2*(j-2)+1];
      float pl = al + bl + dist*wlo;
      float ph = ah + bh + dist*whi;
      mm[2*j]   = (bf16)silu_f(pl);
      mm[2*j+1] = (bf16)silu_f(ph);
    }
    *(bf16x8*)(smem + swz(er + it*32, cq*2)) = mm;
  }
  __syncthreads();

  // GEMM: wave w owns edges [w*16, w*16+16); B-frags straight from global (L1)
  int rsel = lane & 15, hi = lane >> 4;
  f32x4 acc[8];
  #pragma unroll
  for (int n=0;n<8;++n)
    #pragma unroll
    for (int r=0;r<4;++r) acc[n][r]=0.f;
  #pragma unroll
  for (int ks=0;ks<4;++ks){
    bf16x8 fa = *(const bf16x8*)(smem + swz(w*16 + rsel, ks*64 + hi*16));
    #pragma unroll
    for (int n=0;n<8;++n){
      bf16x8 fb = *(const bf16x8*)(w2t + (n*16+rsel)*128 + ks*32 + hi*8);
      acc[n] = mfma16(fa, fb, acc[n]);
    }
  }
  __syncthreads();   // all m1 reads done before m2 overwrites smem

  // m2 = silu(acc + b2) -> bf16, rotation (col + 4*row)&127 (2-way max both sides)
  #pragma unroll
  for (int n=0;n<8;++n){
    int col = n*16 + rsel;
    float bb = b2[col];
    #pragma unroll
    for (int r=0;r<4;++r){
      int row = w*16 + 4*hi + r;
      *(bf16*)(smem + row*256 + (((col + 4*row) & 127) << 1)) = (bf16)silu_f(acc[n][r] + bb);
    }
  }
  __syncthreads();

  // segmented walk: 512 threads = 128 cols x 4 windows of 32 edges
  int col = tid & 127, q = tid >> 7;
  int r0 = q*32;
  int g0 = e0 + r0;
  int prevd = (g0 == 0) ? -1 : ((r0 == 0) ? rec[g0-1].y : s_dst[r0-1]);
  int nextd = (g0 + 32 >= EE) ? -1 : ((r0 + 32 < 128) ? s_dst[r0+32] : rec[g0+32].y);
  float a = 0.f; int cur = s_dst[r0]; bool openL = (cur == prevd);
  #pragma unroll 4
  for (int i=0;i<32;++i){
    int rr = r0 + i;
    unsigned hv = *(const uint16_t*)(smem + rr*256 + (((col + 4*rr) & 127) << 1));
    float v = __uint_as_float(hv << 16);
    int d = s_dst[rr];
    if (d != cur){
      if (openL) atomicAdd(&aggr[(size_t)cur*128 + col], a);
      else       aggr[(size_t)cur*128 + col] = a;
      openL = false; a = v; cur = d;
    } else a += v;
  }
  if (openL || cur == nextd) atomicAdd(&aggr[(size_t)cur*128 + col], a);
  else                       aggr[(size_t)cur*128 + col] = a;
}

// ---------------- pooling + transformer (fp32) ----------------
__device__ __forceinline__ int lbound(const int* a, int n, int key){
  int lo=0, hi=n;
  while (lo<hi){ int mid=(lo+hi)>>1; if (a[mid]<key) lo=mid+1; else hi=mid; }
  return lo;
}

__global__ __launch_bounds__(384) void k_pool_qkv(
    const float* __restrict__ h, const int* __restrict__ batch,
    const float* __restrict__ wq, const float* __restrict__ bq,
    float* __restrict__ gbuf, float* __restrict__ qkvb)
{
  __shared__ float sg[128];
  int gr = blockIdx.x, tid = threadIdx.x;
  if (tid < 128){
    int lo = lbound(batch, NN, gr), hi2 = lbound(batch, NN, gr+1);
    float s = 0.f;
    for (int n=lo;n<hi2;++n) s += h[(size_t)n*HH + tid];
    int c = hi2 - lo; if (c < 1) c = 1;
    s /= (float)c;
    sg[tid] = s; gbuf[gr*128 + tid] = s;
  }
  __syncthreads();
  float a = bq[tid];
  for (int k=0;k<128;++k) a += sg[k]*wq[k*384 + tid];
  qkvb[gr*384 + tid] = a;
}

template<int MODE>
__global__ __launch_bounds__(128) void k_tail(
    const float* __restrict__ qkv, const float* __restrict__ wo,
    const float* __restrict__ bo, const float* __restrict__ l1g,
    const float* __restrict__ l1b, const float* __restrict__ w1,
    const float* __restrict__ b1f, const float* __restrict__ w2,
    const float* __restrict__ b2f, const float* __restrict__ l2g,
    const float* __restrict__ l2b, float* __restrict__ gbuf,
    const float* __restrict__ wq2, const float* __restrict__ bq2,
    float* __restrict__ qkvb2,
    const float* __restrict__ cw1, const float* __restrict__ cb1,
    const float* __restrict__ cw2, const float* __restrict__ cb2,
    float* __restrict__ out)
{
  __shared__ float sq[128];
  __shared__ float ss[4][256];
  __shared__ float so[128];
  __shared__ float st[256];
  __shared__ float red[4];
  int r = blockIdx.x, tid = threadIdx.x;
  sq[tid] = qkv[r*384 + tid];
  __syncthreads();
  const float scale = 0.17677669529663687f;
  for (int i=tid; i<1024; i+=128){
    int hh = i >> 8, j = i & 255;
    const float* kr = qkv + j*384 + 128 + hh*32;
    const float* qr = sq + hh*32;
    float s=0;
    #pragma unroll
    for (int d=0;d<32;++d) s += qr[d]*kr[d];
    ss[hh][j] = s*scale;
  }
  __syncthreads();
  int hh = tid >> 5, sl = tid & 31;
  float m = -1e30f;
  #pragma unroll
  for (int q8=0;q8<8;++q8) m = fmaxf(m, ss[hh][sl + q8*32]);
  #pragma unroll
  for (int off=16; off; off>>=1) m = fmaxf(m, __shfl_xor(m, off, 32));
  float sum = 0.f;
  #pragma unroll
  for (int q8=0;q8<8;++q8){
    float e = __expf(ss[hh][sl+q8*32] - m);
    ss[hh][sl+q8*32] = e;
    sum += e;
  }
  #pragma unroll
  for (int off=16; off; off>>=1) sum += __shfl_xor(sum, off, 32);
  float inv = __builtin_amdgcn_rcpf(sum);
  __syncthreads();
  float accv = 0.f;
  for (int j=0;j<256;++j) accv += ss[hh][j]*qkv[j*384 + 256 + hh*32 + sl];
  so[tid] = accv*inv;
  __syncthreads();
  float a = bo[tid];
  for (int k=0;k<128;++k) a += so[k]*wo[k*128 + tid];
  float val = gbuf[r*128 + tid] + a;
  {
    float s = val, q = val*val;
    #pragma unroll
    for (int off=32; off; off>>=1){ s += __shfl_xor(s, off); q += __shfl_xor(q, off); }
    int lane = tid & 63, wv = tid >> 6;
    if (lane==0){ red[wv*2]=s; red[wv*2+1]=q; }
    __syncthreads();
    float S = red[0]+red[2], Q = red[1]+red[3];
    float mean = S*(1.0f/128.0f);
    float var = Q*(1.0f/128.0f) - mean*mean;
    float ninv = rsqrtf(var + 1e-5f);
    val = (val-mean)*ninv*l1g[tid] + l1b[tid];
  }
  sq[tid] = val;
  __syncthreads();
  float a0 = b1f[tid], a1 = b1f[tid+128];
  for (int k=0;k<128;++k){
    float gv = sq[k];
    a0 += gv*w1[k*256 + tid];
    a1 += gv*w1[k*256 + tid + 128];
  }
  st[tid]     = fmaxf(a0, 0.f);
  st[tid+128] = fmaxf(a1, 0.f);
  __syncthreads();
  float b = b2f[tid];
  for (int k=0;k<256;++k) b += st[k]*w2[k*128 + tid];
  float val2 = val + b;
  {
    float s = val2, q = val2*val2;
    #pragma unroll
    for (int off=32; off; off>>=1){ s += __shfl_xor(s, off); q += __shfl_xor(q, off); }
    int lane = tid & 63, wv = tid >> 6;
    __syncthreads();
    if (lane==0){ red[wv*2]=s; red[wv*2+1]=q; }
    __syncthreads();
    float S = red[0]+red[2], Q = red[1]+red[3];
    float mean = S*(1.0f/128.0f);
    float var = Q*(1.0f/128.0f) - mean*mean;
    float ninv = rsqrtf(var + 1e-5f);
    val2 = (val2-mean)*ninv*l2g[tid] + l2b[tid];
  }
  gbuf[r*128 + tid] = val2;
  if (MODE == 0){
    sq[tid] = val2;
    __syncthreads();
    float q0 = bq2[tid], q1 = bq2[tid+128], q2 = bq2[tid+256];
    for (int k=0;k<128;++k){
      float gv = sq[k];
      const float* wr = wq2 + k*384;
      q0 += gv*wr[tid]; q1 += gv*wr[tid+128]; q2 += gv*wr[tid+256];
    }
    qkvb2[r*384+tid]=q0; qkvb2[r*384+tid+128]=q1; qkvb2[r*384+tid+256]=q2;
  }
  if (MODE == 1){
    so[tid] = val2;
    __syncthreads();
    if (tid < 64){
      float c = cb1[tid];
      for (int k=0;k<128;++k) c += so[k]*cw1[k*64 + tid];
      c = fmaxf(c, 0.f);
      float p = c * cw2[tid];
      #pragma unroll
      for (int off=32; off; off>>=1) p += __shfl_xor(p, off);
      if (tid==0) out[r] = p + cb2[0];
    }
  }
}

// ---------------- launch ----------------
extern "C" void kernel_launch(void* const* d_in, const int* in_sizes, int n_in,
                              void* d_out, int out_size, void* d_ws, size_t ws_size,
                              hipStream_t stream)
{
  (void)in_sizes; (void)n_in; (void)out_size; (void)ws_size;
  const float* x      = (const float*)d_in[0];
  const float* pos    = (const float*)d_in[1];
  const float* emb_w  = (const float*)d_in[2];
  const float* emb_b  = (const float*)d_in[3];
  const float* edge_w1= (const float*)d_in[4];
  const float* edge_b1= (const float*)d_in[5];
  const float* edge_w2= (const float*)d_in[6];
  const float* edge_b2= (const float*)d_in[7];
  const float* node_w1= (const float*)d_in[8];
  const float* node_b1= (const float*)d_in[9];
  const float* node_w2= (const float*)d_in[10];
  const float* node_b2= (const float*)d_in[11];
  const float* qkv_w  = (const float*)d_in[12];
  const float* qkv_b  = (const float*)d_in[13];
  const float* out_w  = (const float*)d_in[14];
  const float* out_b  = (const float*)d_in[15];
  const float* ln1_g  = (const float*)d_in[16];
  const float* ln1_b  = (const float*)d_in[17];
  const float* ln2_g  = (const float*)d_in[18];
  const float* ln2_b  = (const float*)d_in[19];
  const float* ff_w1  = (const float*)d_in[20];
  const float* ff_b1  = (const float*)d_in[21];
  const float* ff_w2  = (const float*)d_in[22];
  const float* ff_b2  = (const float*)d_in[23];
  const float* cls_w1 = (const float*)d_in[24];
  const float* cls_b1 = (const float*)d_in[25];
  const float* cls_w2 = (const float*)d_in[26];
  const float* cls_b2 = (const float*)d_in[27];
  const int* ei       = (const int*)d_in[28];
  const int* batch    = (const int*)d_in[29];
  float* out = (float*)d_out;

  uint8_t* wp = (uint8_t*)d_ws;
  auto take = [&](size_t nb)->void*{ void* r = wp; wp += (nb + 255) & ~(size_t)255; return r; };
  float* h      = (float*)take((size_t)NN*HH*4);
  bf16*  h_bf   = (bf16*) take((size_t)NN*HH*2);
  bf16*  P      = (bf16*) take((size_t)NN*256*2);
  float* aggr   = (float*)take((size_t)NN*HH*4);
  bf16*  u1     = (bf16*) take((size_t)NN*HH*2);
  int*   cnt    = (int*)  take((size_t)NN*4);
  int*   cursor = (int*)  take((size_t)NN*4);
  int4*  rec    = (int4*) take((size_t)EE*16);
  bf16*  wcatT  = (bf16*) take((size_t)3*256*128*2);
  bf16*  w2T    = (bf16*) take((size_t)3*128*128*2);
  bf16*  nw1T   = (bf16*) take((size_t)3*128*256*2);
  bf16*  nw2T   = (bf16*) take((size_t)3*128*128*2);
  float* bcat   = (float*)take((size_t)3*256*4);
  float* gbuf   = (float*)take((size_t)GG*HH*4);
  float* qkvb   = (float*)take((size_t)GG*384*4);
  float* qkvb2  = (float*)take((size_t)GG*384*4);

  dim3 b256(256);
  k_prep<<<dim3(21312), b256, 0, stream>>>(edge_w1, edge_w2, node_w1, node_w2,
    edge_b1, x, emb_w, emb_b, wcatT, w2T, nw1T, nw2T, bcat, h, h_bf, cnt);
  k_hist<<<dim3(EE/256), b256, 0, stream>>>(ei + EE, cnt);
  k_scan<<<dim3(1), dim3(1024), 0, stream>>>(cnt, cursor, NN);
  k_scatter<<<dim3(EE/256), b256, 0, stream>>>(ei, pos, cursor, rec);

  for (int l=0;l<3;++l){
    k_gemm<128,128,0,true,true,false,true,false,true><<<dim3(313,4), b256, 0, stream>>>(
      h_bf, nullptr, wcatT + (size_t)l*256*128, bcat + (size_t)l*256, nullptr, P, nullptr, 256, aggr);
    k_edge<<<dim3(EE/128), dim3(512), 0, stream>>>(P, w2T + (size_t)l*128*128,
      edge_w1 + ((size_t)l*257 + 256)*128, edge_b2 + (size_t)l*128, rec, aggr);
    k_gemm<256,128,1,true,true,false,true,false,false><<<dim3(313,2), b256, 0, stream>>>(
      h_bf, aggr, nw1T + (size_t)l*128*256, node_b1 + (size_t)l*128, nullptr, u1, nullptr, 128, nullptr);
    k_gemm<128,128,0,true,true,true,true,true,false><<<dim3(313,2), b256, 0, stream>>>(
      u1, nullptr, nw2T + (size_t)l*128*128, node_b2 + (size_t)l*128, h, h_bf, h, 128, nullptr);
  }

  k_pool_qkv<<<dim3(GG), dim3(384), 0, stream>>>(h, batch, qkv_w, qkv_b, gbuf, qkvb);
  k_tail<0><<<dim3(GG), dim3(128), 0, stream>>>(qkvb, out_w, out_b,
    ln1_g, ln1_b, ff_w1, ff_b1, ff_w2, ff_b2, ln2_g, ln2_b, gbuf,
    qkv_w + (size_t)128*384, qkv_b + 384, qkvb2,
    nullptr, nullptr, nullptr, nullptr, nullptr);
  k_tail<1><<<dim3(GG), dim3(128), 0, stream>>>(qkvb2, out_w + (size_t)128*128, out_b + 128,
    ln1_g + 128, ln1_b + 128, ff_w1 + (size_t)128*256, ff_b1 + 256,
    ff_w2 + (size_t)256*128, ff_b2 + 128, ln2_g + 128, ln2_b + 128, gbuf,
    nullptr, nullptr, nullptr,
    cls_w1, cls_b1, cls_w2, cls_b2, out);
}

// Round 5
// 727.056 us; speedup vs baseline: 1.4476x; 1.4476x over previous
//
#include <hip/hip_runtime.h>
#include <hip/hip_bf16.h>
#include <stdint.h>

#define NN 40000
#define EE 640000
#define GG 256
#define FFE 9
#define HH 128

typedef __bf16 bf16;
typedef __bf16 bf16x8 __attribute__((ext_vector_type(8)));
typedef float f32x4 __attribute__((ext_vector_type(4)));

__device__ __forceinline__ f32x4 mfma16(bf16x8 a, bf16x8 b, f32x4 c){
  return __builtin_amdgcn_mfma_f32_16x16x32_bf16(a, b, c, 0, 0, 0);
}
__device__ __forceinline__ float silu_f(float x){
  return x * __builtin_amdgcn_rcpf(1.0f + __expf(-x));
}
__device__ __forceinline__ uint16_t bfb(float x){ bf16 h=(bf16)x; return *(uint16_t*)&h; }
// byte-offset XOR swizzle for [row][256B] LDS tiles
__device__ __forceinline__ int swz(int row, int cb){
  return row*256 + (cb ^ ((row & 7) << 4));
}

// ---------------- merged prep ----------------
__global__ __launch_bounds__(256) void k_prep(
    const float* __restrict__ edge_w1, const float* __restrict__ edge_w2,
    const float* __restrict__ node_w1, const float* __restrict__ node_w2,
    const float* __restrict__ edge_b1,
    const float* __restrict__ x, const float* __restrict__ emb_w,
    const float* __restrict__ emb_b,
    bf16* __restrict__ wcatT, bf16* __restrict__ w2T,
    bf16* __restrict__ nw1T, bf16* __restrict__ nw2T,
    float* __restrict__ bcat, float* __restrict__ h, bf16* __restrict__ h_bf,
    int* __restrict__ cnt)
{
  int b = blockIdx.x, tid = threadIdx.x;
  if (b < 192){
    int l = b/64; int t2 = (b%64)*256 + tid;
    int n = t2 >> 7, k = t2 & 127;
    wcatT[(size_t)l*32768 + n*128 + k] = (bf16)edge_w1[(size_t)l*32896 + k*128 + n];
  } else if (b < 384){
    int lb = b - 192; int l = lb/64; int t2 = (lb%64)*256 + tid;
    int n = t2 >> 7, k = t2 & 127;
    wcatT[(size_t)l*32768 + 16384 + n*128 + k] = (bf16)edge_w1[(size_t)l*32896 + (128+k)*128 + n];
  } else if (b < 576){
    int lb = b - 384; int l = lb/64; int t2 = (lb%64)*256 + tid;
    int n = t2 >> 7, k = t2 & 127;
    w2T[(size_t)l*16384 + n*128 + k] = (bf16)edge_w2[(size_t)l*16384 + k*128 + n];
  } else if (b < 960){
    int lb = b - 576; int l = lb/128; int t2 = (lb%128)*256 + tid;
    int n = t2 >> 8, k = t2 & 255;
    nw1T[(size_t)l*32768 + n*256 + k] = (bf16)node_w1[(size_t)l*32768 + k*128 + n];
  } else if (b < 1152){
    int lb = b - 960; int l = lb/64; int t2 = (lb%64)*256 + tid;
    int n = t2 >> 7, k = t2 & 127;
    nw2T[(size_t)l*16384 + n*128 + k] = (bf16)node_w2[(size_t)l*16384 + k*128 + n];
  } else if (b < 1155){
    int l = b - 1152;
    bcat[l*256 + tid] = (tid < 128) ? edge_b1[l*128 + tid] : 0.0f;
  } else if (b < 1312){
    int i = (b - 1155)*256 + tid;
    if (i < NN) cnt[i] = 0;
  } else {
    int idx = (b - 1312)*256 + tid;
    int n = idx >> 7, f = idx & 127;
    float s = emb_b[f];
    const float* xr = x + n*FFE;
    #pragma unroll
    for (int k=0;k<FFE;++k) s += xr[k]*emb_w[k*HH + f];
    h[idx] = s;
    h_bf[idx] = (bf16)s;
  }
}

// ---------------- counting sort by dst ----------------
__global__ __launch_bounds__(256) void k_hist(const int* __restrict__ dst, int* __restrict__ cnt){
  int e = blockIdx.x*256 + threadIdx.x;
  if (e < EE) atomicAdd(&cnt[dst[e]], 1);
}

__global__ __launch_bounds__(1024) void k_scan(const int* __restrict__ cnt, int* __restrict__ cursor, int n){
  __shared__ int s_wsum[16];
  __shared__ int s_run;
  int tid = threadIdx.x, lane = tid & 63, wv = tid >> 6;
  if (tid == 0) s_run = 0;
  __syncthreads();
  for (int base=0; base<n; base+=4096){
    int i = base + tid*4;
    int c0 = (i  <n)? cnt[i  ] : 0;
    int c1 = (i+1<n)? cnt[i+1] : 0;
    int c2 = (i+2<n)? cnt[i+2] : 0;
    int c3 = (i+3<n)? cnt[i+3] : 0;
    int t0 = c0, t1 = t0+c1, t2 = t1+c2, t3 = t2+c3;
    int xx = t3;
    #pragma unroll
    for (int off=1; off<64; off<<=1){ int t = __shfl_up(xx, off); if (lane>=off) xx += t; }
    if (lane==63) s_wsum[wv] = xx;
    __syncthreads();
    if (wv==0 && lane<16){
      int y = s_wsum[lane];
      #pragma unroll
      for (int off=1; off<16; off<<=1){ int t = __shfl_up(y, off, 16); if (lane>=off) y += t; }
      s_wsum[lane] = y;
    }
    __syncthreads();
    int woff = wv ? s_wsum[wv-1] : 0;
    int run = s_run;
    int eb = run + woff + xx - t3;
    if (i  <n) cursor[i  ] = eb;
    if (i+1<n) cursor[i+1] = eb + t0;
    if (i+2<n) cursor[i+2] = eb + t1;
    if (i+3<n) cursor[i+3] = eb + t2;
    __syncthreads();
    if (tid==0) s_run = run + s_wsum[15];
    __syncthreads();
  }
}

__global__ __launch_bounds__(256) void k_scatter(
    const int* __restrict__ ei, const float* __restrict__ pos,
    int* __restrict__ cursor, int4* __restrict__ rec)
{
  int e = blockIdx.x*256 + threadIdx.x;
  if (e >= EE) return;
  int s = ei[e], d = ei[EE + e];
  int p = atomicAdd(&cursor[d], 1);
  float dx = pos[d*3+0]-pos[s*3+0];
  float dy = pos[d*3+1]-pos[s*3+1];
  float dz = pos[d*3+2]-pos[s*3+2];
  int4 rc; rc.x = s; rc.y = d; rc.z = __float_as_int(sqrtf(dx*dx+dy*dy+dz*dz)); rc.w = 0;
  rec[p] = rc;
}

// ---------------- 128x64-tile bf16 MFMA GEMM ----------------
template<int KTOT, int K1, int ACT, bool A1BF, bool BIAS, bool RESID, bool OBF, bool OF, bool ZAGGR>
__global__ __launch_bounds__(256) void k_gemm(
    const void* __restrict__ a1v, const float* __restrict__ a2,
    const bf16* __restrict__ wt, const float* __restrict__ bias,
    const float* __restrict__ resid, bf16* __restrict__ outb,
    float* __restrict__ outf, int Nw, float* __restrict__ aggr)
{
  constexpr int LDK = 136;
  __shared__ bf16 s_a[128*LDK];
  __shared__ bf16 s_w[64*LDK];
  int tid = threadIdx.x, lane = tid & 63, w = tid >> 6;
  int m0 = blockIdx.x*128, n0 = blockIdx.y*64;
  if (ZAGGR && blockIdx.y == 0){
    int nrows = NN - m0; if (nrows > 128) nrows = 128;
    f32x4 z = {0.f,0.f,0.f,0.f};
    for (int i = tid; i < nrows*32; i += 256)
      *(f32x4*)(aggr + (size_t)m0*128 + (size_t)i*4) = z;
  }
  f32x4 acc[2][4];
  #pragma unroll
  for (int i=0;i<2;++i)
    #pragma unroll
    for (int j=0;j<4;++j)
      #pragma unroll
      for (int r=0;r<4;++r) acc[i][j][r]=0.f;
  int rsel = lane & 15, ksel = (lane>>4)*8;
  int wm = w*32;

  for (int kh=0; kh<KTOT; kh+=128){
    #pragma unroll
    for (int it=0; it<8; ++it){
      int idx = tid + it*256;
      int row = idx >> 4, col = (idx & 15)*8;
      int gc = kh + col;
      int grow = m0 + row; if (grow > NN-1) grow = NN-1;
      bf16x8 vv;
      if (gc < K1){
        if (A1BF){
          vv = *(const bf16x8*)((const bf16*)a1v + (size_t)grow*K1 + gc);
        } else {
          const float* srcp = (const float*)a1v + (size_t)grow*K1 + gc;
          f32x4 u0 = *(const f32x4*)srcp;
          f32x4 u1 = *(const f32x4*)(srcp+4);
          vv[0]=(bf16)u0[0]; vv[1]=(bf16)u0[1]; vv[2]=(bf16)u0[2]; vv[3]=(bf16)u0[3];
          vv[4]=(bf16)u1[0]; vv[5]=(bf16)u1[1]; vv[6]=(bf16)u1[2]; vv[7]=(bf16)u1[3];
        }
      } else {
        const float* srcp = a2 + (size_t)grow*(KTOT-K1) + (gc-K1);
        f32x4 u0 = *(const f32x4*)srcp;
        f32x4 u1 = *(const f32x4*)(srcp+4);
        vv[0]=(bf16)u0[0]; vv[1]=(bf16)u0[1]; vv[2]=(bf16)u0[2]; vv[3]=(bf16)u0[3];
        vv[4]=(bf16)u1[0]; vv[5]=(bf16)u1[1]; vv[6]=(bf16)u1[2]; vv[7]=(bf16)u1[3];
      }
      *(bf16x8*)&s_a[row*LDK + col] = vv;
    }
    #pragma unroll
    for (int it=0; it<4; ++it){
      int idx = tid + it*256;
      int row = idx >> 4, col = (idx & 15)*8;
      *(bf16x8*)&s_w[row*LDK + col] = *(const bf16x8*)(wt + (size_t)(n0+row)*KTOT + kh + col);
    }
    __syncthreads();
    #pragma unroll
    for (int ks=0; ks<4; ++ks){
      int kb = ks*32 + ksel;
      bf16x8 fa0 = *(const bf16x8*)&s_a[(wm+rsel)*LDK + kb];
      bf16x8 fa1 = *(const bf16x8*)&s_a[(wm+16+rsel)*LDK + kb];
      #pragma unroll
      for (int j=0;j<4;++j){
        bf16x8 fb = *(const bf16x8*)&s_w[(j*16+rsel)*LDK + kb];
        acc[0][j]=mfma16(fa0,fb,acc[0][j]);
        acc[1][j]=mfma16(fa1,fb,acc[1][j]);
      }
    }
    __syncthreads();
  }

  #pragma unroll
  for (int i=0;i<2;++i){
    #pragma unroll
    for (int j=0;j<4;++j){
      int col = n0 + j*16 + rsel;
      float bv = BIAS ? bias[col] : 0.0f;
      #pragma unroll
      for (int r=0;r<4;++r){
        int row = m0 + wm + i*16 + 4*(lane>>4) + r;
        if (row < NN){
          float v = acc[i][j][r] + bv;
          if (ACT==1) v = silu_f(v);
          if (RESID) v += resid[(size_t)row*Nw + col];
          if (OBF) outb[(size_t)row*Nw + col] = (bf16)v;
          if (OF)  outf[(size_t)row*Nw + col] = v;
        }
      }
    }
  }
}

// ---------------- fused edge MLP + MFMA-based segmented aggregation (v5) ----------------
// 128 edges/block, 512 threads, ~34KB LDS. Wave w owns output cols [w*16,w*16+16).
// w2 fragments held in registers (loaded once). m2 written transposed [col][e] bf16
// into the same LDS buffer; aggregation = Sel @ m2^T via a second MFMA pass.
__global__ __launch_bounds__(512, 6) void k_edge(
    const bf16* __restrict__ P, const bf16* __restrict__ w2t,
    const float* __restrict__ w1r, const float* __restrict__ b2,
    const int4* __restrict__ rec, float* __restrict__ aggr)
{
  __shared__ char smem[32768];      // m1 [128 e][256B] swz -> m2t [128 col][256B] swz
  __shared__ int s_dst[128];
  __shared__ unsigned s_segidw[32]; // 128 segids packed u8
  __shared__ int s_segdst[128];
  __shared__ int s_misc[4];         // 0 prevd, 1 nextd, 2 nseg
  int tid = threadIdx.x, lane = tid & 63, w = tid >> 6;
  int rsel = lane & 15, hi = lane >> 4;
  int bid = blockIdx.x;
  int swb = (bid & 7) * (EE/128/8) + (bid >> 3);   // XCD-chunked, 5000%8==0
  int e0 = swb * 128;
  int col = w*16 + rsel;

  // w2 B-fragments for this wave's col-block: 4 x 16B from global, once
  bf16x8 fb[4];
  #pragma unroll
  for (int ks=0;ks<4;++ks)
    fb[ks] = *(const bf16x8*)(w2t + (size_t)col*128 + ks*32 + hi*8);

  if (tid == 0){
    s_misc[0] = (e0 == 0) ? -2147483647 : rec[e0-1].y;
    s_misc[1] = (e0 + 128 >= EE) ? -2147483647 : rec[e0+128].y;
  }

  // ---- m1 = silu(PA[dst] + PB[src] + dist*w1r)  (b1 folded into P bias)
  int cq = (tid & 15)*8;
  int er = tid >> 5;                // 0..15 -> wait: 512/16 = 32 edge-threads? keep er = tid>>4
  er = tid >> 4;                    // 0..31
  int4 rc[4];
  #pragma unroll
  for (int it=0; it<4; ++it) rc[it] = rec[e0 + er + it*32];
  uint4 pau[4], pbu[4];
  #pragma unroll
  for (int it=0; it<4; ++it){
    pau[it] = *(const uint4*)(P + ((size_t)rc[it].y << 8) + cq);
    pbu[it] = *(const uint4*)(P + ((size_t)rc[it].x << 8) + 128 + cq);
  }
  if (cq == 0){
    #pragma unroll
    for (int it=0; it<4; ++it) s_dst[er + it*32] = rc[it].y;
  }
  f32x4 wr0 = *(const f32x4*)(w1r + cq);
  f32x4 wr1 = *(const f32x4*)(w1r + cq + 4);
  #pragma unroll
  for (int it=0; it<4; ++it){
    float dist = __int_as_float(rc[it].z);
    bf16x8 mm;
    #pragma unroll
    for (int j=0;j<4;++j){
      unsigned ua = ((const unsigned*)&pau[it])[j];
      unsigned ub = ((const unsigned*)&pbu[it])[j];
      float al = __uint_as_float(ua << 16);
      float ah = __uint_as_float(ua & 0xFFFF0000u);
      float bl = __uint_as_float(ub << 16);
      float bh = __uint_as_float(ub & 0xFFFF0000u);
      float wlo = (j<2) ? wr0[2*j]   : wr1[2*(j-2)];
      float whi = (j<2) ? wr0[2*j+1] : wr1[2*(j-2)+1];
      mm[2*j]   = (bf16)silu_f(al + bl + dist*wlo);
      mm[2*j+1] = (bf16)silu_f(ah + bh + dist*whi);
    }
    *(bf16x8*)(smem + swz(er + it*32, cq*2)) = mm;
  }
  __syncthreads();

  // ---- segid scan over 128 sorted dsts (wave 0; 2 edges/lane)
  if (w == 0){
    int d0 = s_dst[2*lane], d1 = s_dst[2*lane+1];
    int dm1 = (lane == 0) ? 0 : s_dst[2*lane-1];
    int h0 = (lane == 0) ? 1 : (d0 != dm1);
    int h1 = (d1 != d0);
    int p = h0 + h1, x = p;
    #pragma unroll
    for (int off=1; off<64; off<<=1){ int t = __shfl_up(x, off); if (lane>=off) x += t; }
    int excl = x - p;
    int id0 = excl + h0 - 1;
    int id1 = excl + p - 1;
    uint8_t* sb = (uint8_t*)s_segidw;
    sb[2*lane]   = (uint8_t)id0;
    sb[2*lane+1] = (uint8_t)id1;
    if (h0) s_segdst[id0] = d0;
    if (h1) s_segdst[id1] = d1;
    if (lane == 63) s_misc[2] = id1 + 1;
  }

  // ---- GEMM1: C[e][col] = m1 @ w2^T, wave covers all 128 edges x its 16 cols
  f32x4 acc[8];
  #pragma unroll
  for (int mt=0;mt<8;++mt)
    #pragma unroll
    for (int r=0;r<4;++r) acc[mt][r]=0.f;
  #pragma unroll
  for (int mt=0;mt<8;++mt){
    #pragma unroll
    for (int ks=0;ks<4;++ks){
      bf16x8 fa = *(const bf16x8*)(smem + swz(mt*16 + rsel, ks*64 + hi*16));
      acc[mt] = mfma16(fa, fb[ks], acc[mt]);
    }
  }
  __syncthreads();   // all m1 reads + scan writes done

  // ---- m2^T = silu(acc + b2) -> bf16 [col][e] swizzled, aliased on smem
  float bb = b2[col];
  #pragma unroll
  for (int mt=0;mt<8;++mt){
    uint2 pk;
    pk.x = (unsigned)bfb(silu_f(acc[mt][0] + bb)) | ((unsigned)bfb(silu_f(acc[mt][1] + bb)) << 16);
    pk.y = (unsigned)bfb(silu_f(acc[mt][2] + bb)) | ((unsigned)bfb(silu_f(acc[mt][3] + bb)) << 16);
    *(uint2*)(smem + col*256 + ((mt*32 + hi*8) ^ ((col & 7) << 4))) = pk;
  }
  __syncthreads();

  // ---- GEMM2: R[s][col] = Sel @ m2^T ; store (interior) / atomic (boundary)
  bf16x8 gb[4];
  #pragma unroll
  for (int ks=0;ks<4;++ks)
    gb[ks] = *(const bf16x8*)(smem + col*256 + ((ks*64 + hi*16) ^ ((col & 7) << 4)));
  int nseg = s_misc[2];
  bool openL = (s_dst[0]   == s_misc[0]);
  bool openR = (s_dst[127] == s_misc[1]);
  for (int st = 0; st < nseg; st += 16){
    unsigned tgt = (unsigned)(st + rsel);
    f32x4 racc = {0.f,0.f,0.f,0.f};
    #pragma unroll
    for (int ks=0;ks<4;++ks){
      unsigned w0 = s_segidw[ks*8 + hi*2];
      unsigned w1 = s_segidw[ks*8 + hi*2 + 1];
      union { uint16_t u[8]; bf16x8 v; } sa;
      #pragma unroll
      for (int j=0;j<4;++j){
        sa.u[j]   = (((w0 >> (8*j)) & 255u) == tgt) ? (uint16_t)0x3F80 : (uint16_t)0;
        sa.u[4+j] = (((w1 >> (8*j)) & 255u) == tgt) ? (uint16_t)0x3F80 : (uint16_t)0;
      }
      racc = mfma16(sa.v, gb[ks], racc);
    }
    #pragma unroll
    for (int r=0;r<4;++r){
      int s = st + 4*hi + r;
      if (s < nseg){
        float v = racc[r];
        size_t off = (size_t)s_segdst[s]*128 + col;
        bool atom = (s == 0 && openL) || (s == nseg-1 && openR);
        if (atom) atomicAdd(&aggr[off], v);
        else      aggr[off] = v;
      }
    }
  }
}

// ---------------- pooling + transformer (fp32) ----------------
__device__ __forceinline__ int lbound(const int* a, int n, int key){
  int lo=0, hi=n;
  while (lo<hi){ int mid=(lo+hi)>>1; if (a[mid]<key) lo=mid+1; else hi=mid; }
  return lo;
}

__global__ __launch_bounds__(384) void k_pool_qkv(
    const float* __restrict__ h, const int* __restrict__ batch,
    const float* __restrict__ wq, const float* __restrict__ bq,
    float* __restrict__ gbuf, float* __restrict__ qkvb)
{
  __shared__ float sg[128];
  int gr = blockIdx.x, tid = threadIdx.x;
  if (tid < 128){
    int lo = lbound(batch, NN, gr), hi2 = lbound(batch, NN, gr+1);
    float s = 0.f;
    for (int n=lo;n<hi2;++n) s += h[(size_t)n*HH + tid];
    int c = hi2 - lo; if (c < 1) c = 1;
    s /= (float)c;
    sg[tid] = s; gbuf[gr*128 + tid] = s;
  }
  __syncthreads();
  float a = bq[tid];
  for (int k=0;k<128;++k) a += sg[k]*wq[k*384 + tid];
  qkvb[gr*384 + tid] = a;
}

template<int MODE>
__global__ __launch_bounds__(128) void k_tail(
    const float* __restrict__ qkv, const float* __restrict__ wo,
    const float* __restrict__ bo, const float* __restrict__ l1g,
    const float* __restrict__ l1b, const float* __restrict__ w1,
    const float* __restrict__ b1f, const float* __restrict__ w2,
    const float* __restrict__ b2f, const float* __restrict__ l2g,
    const float* __restrict__ l2b, float* __restrict__ gbuf,
    const float* __restrict__ wq2, const float* __restrict__ bq2,
    float* __restrict__ qkvb2,
    const float* __restrict__ cw1, const float* __restrict__ cb1,
    const float* __restrict__ cw2, const float* __restrict__ cb2,
    float* __restrict__ out)
{
  __shared__ float sq[128];
  __shared__ float ss[4][256];
  __shared__ float so[128];
  __shared__ float st[256];
  __shared__ float red[4];
  int r = blockIdx.x, tid = threadIdx.x;
  sq[tid] = qkv[r*384 + tid];
  __syncthreads();
  const float scale = 0.17677669529663687f;
  for (int i=tid; i<1024; i+=128){
    int hh = i >> 8, j = i & 255;
    const float* kr = qkv + j*384 + 128 + hh*32;
    const float* qr = sq + hh*32;
    float s=0;
    #pragma unroll
    for (int d=0;d<32;++d) s += qr[d]*kr[d];
    ss[hh][j] = s*scale;
  }
  __syncthreads();
  int hh = tid >> 5, sl = tid & 31;
  float m = -1e30f;
  #pragma unroll
  for (int q8=0;q8<8;++q8) m = fmaxf(m, ss[hh][sl + q8*32]);
  #pragma unroll
  for (int off=16; off; off>>=1) m = fmaxf(m, __shfl_xor(m, off, 32));
  float sum = 0.f;
  #pragma unroll
  for (int q8=0;q8<8;++q8){
    float e = __expf(ss[hh][sl+q8*32] - m);
    ss[hh][sl+q8*32] = e;
    sum += e;
  }
  #pragma unroll
  for (int off=16; off; off>>=1) sum += __shfl_xor(sum, off, 32);
  float inv = __builtin_amdgcn_rcpf(sum);
  __syncthreads();
  float accv = 0.f;
  for (int j=0;j<256;++j) accv += ss[hh][j]*qkv[j*384 + 256 + hh*32 + sl];
  so[tid] = accv*inv;
  __syncthreads();
  float a = bo[tid];
  for (int k=0;k<128;++k) a += so[k]*wo[k*128 + tid];
  float val = gbuf[r*128 + tid] + a;
  {
    float s = val, q = val*val;
    #pragma unroll
    for (int off=32; off; off>>=1){ s += __shfl_xor(s, off); q += __shfl_xor(q, off); }
    int lane = tid & 63, wv = tid >> 6;
    if (lane==0){ red[wv*2]=s; red[wv*2+1]=q; }
    __syncthreads();
    float S = red[0]+red[2], Q = red[1]+red[3];
    float mean = S*(1.0f/128.0f);
    float var = Q*(1.0f/128.0f) - mean*mean;
    float ninv = rsqrtf(var + 1e-5f);
    val = (val-mean)*ninv*l1g[tid] + l1b[tid];
  }
  sq[tid] = val;
  __syncthreads();
  float a0 = b1f[tid], a1 = b1f[tid+128];
  for (int k=0;k<128;++k){
    float gv = sq[k];
    a0 += gv*w1[k*256 + tid];
    a1 += gv*w1[k*256 + tid + 128];
  }
  st[tid]     = fmaxf(a0, 0.f);
  st[tid+128] = fmaxf(a1, 0.f);
  __syncthreads();
  float b = b2f[tid];
  for (int k=0;k<256;++k) b += st[k]*w2[k*128 + tid];
  float val2 = val + b;
  {
    float s = val2, q = val2*val2;
    #pragma unroll
    for (int off=32; off; off>>=1){ s += __shfl_xor(s, off); q += __shfl_xor(q, off); }
    int lane = tid & 63, wv = tid >> 6;
    __syncthreads();
    if (lane==0){ red[wv*2]=s; red[wv*2+1]=q; }
    __syncthreads();
    float S = red[0]+red[2], Q = red[1]+red[3];
    float mean = S*(1.0f/128.0f);
    float var = Q*(1.0f/128.0f) - mean*mean;
    float ninv = rsqrtf(var + 1e-5f);
    val2 = (val2-mean)*ninv*l2g[tid] + l2b[tid];
  }
  gbuf[r*128 + tid] = val2;
  if (MODE == 0){
    sq[tid] = val2;
    __syncthreads();
    float q0 = bq2[tid], q1 = bq2[tid+128], q2 = bq2[tid+256];
    for (int k=0;k<128;++k){
      float gv = sq[k];
      const float* wr = wq2 + k*384;
      q0 += gv*wr[tid]; q1 += gv*wr[tid+128]; q2 += gv*wr[tid+256];
    }
    qkvb2[r*384+tid]=q0; qkvb2[r*384+tid+128]=q1; qkvb2[r*384+tid+256]=q2;
  }
  if (MODE == 1){
    so[tid] = val2;
    __syncthreads();
    if (tid < 64){
      float c = cb1[tid];
      for (int k=0;k<128;++k) c += so[k]*cw1[k*64 + tid];
      c = fmaxf(c, 0.f);
      float p = c * cw2[tid];
      #pragma unroll
      for (int off=32; off; off>>=1) p += __shfl_xor(p, off);
      if (tid==0) out[r] = p + cb2[0];
    }
  }
}

// ---------------- launch ----------------
extern "C" void kernel_launch(void* const* d_in, const int* in_sizes, int n_in,
                              void* d_out, int out_size, void* d_ws, size_t ws_size,
                              hipStream_t stream)
{
  (void)in_sizes; (void)n_in; (void)out_size; (void)ws_size;
  const float* x      = (const float*)d_in[0];
  const float* pos    = (const float*)d_in[1];
  const float* emb_w  = (const float*)d_in[2];
  const float* emb_b  = (const float*)d_in[3];
  const float* edge_w1= (const float*)d_in[4];
  const float* edge_b1= (const float*)d_in[5];
  const float* edge_w2= (const float*)d_in[6];
  const float* edge_b2= (const float*)d_in[7];
  const float* node_w1= (const float*)d_in[8];
  const float* node_b1= (const float*)d_in[9];
  const float* node_w2= (const float*)d_in[10];
  const float* node_b2= (const float*)d_in[11];
  const float* qkv_w  = (const float*)d_in[12];
  const float* qkv_b  = (const float*)d_in[13];
  const float* out_w  = (const float*)d_in[14];
  const float* out_b  = (const float*)d_in[15];
  const float* ln1_g  = (const float*)d_in[16];
  const float* ln1_b  = (const float*)d_in[17];
  const float* ln2_g  = (const float*)d_in[18];
  const float* ln2_b  = (const float*)d_in[19];
  const float* ff_w1  = (const float*)d_in[20];
  const float* ff_b1  = (const float*)d_in[21];
  const float* ff_w2  = (const float*)d_in[22];
  const float* ff_b2  = (const float*)d_in[23];
  const float* cls_w1 = (const float*)d_in[24];
  const float* cls_b1 = (const float*)d_in[25];
  const float* cls_w2 = (const float*)d_in[26];
  const float* cls_b2 = (const float*)d_in[27];
  const int* ei       = (const int*)d_in[28];
  const int* batch    = (const int*)d_in[29];
  float* out = (float*)d_out;

  uint8_t* wp = (uint8_t*)d_ws;
  auto take = [&](size_t nb)->void*{ void* r = wp; wp += (nb + 255) & ~(size_t)255; return r; };
  float* h      = (float*)take((size_t)NN*HH*4);
  bf16*  h_bf   = (bf16*) take((size_t)NN*HH*2);
  bf16*  P      = (bf16*) take((size_t)NN*256*2);
  float* aggr   = (float*)take((size_t)NN*HH*4);
  bf16*  u1     = (bf16*) take((size_t)NN*HH*2);
  int*   cnt    = (int*)  take((size_t)NN*4);
  int*   cursor = (int*)  take((size_t)NN*4);
  int4*  rec    = (int4*) take((size_t)EE*16);
  bf16*  wcatT  = (bf16*) take((size_t)3*256*128*2);
  bf16*  w2T    = (bf16*) take((size_t)3*128*128*2);
  bf16*  nw1T   = (bf16*) take((size_t)3*128*256*2);
  bf16*  nw2T   = (bf16*) take((size_t)3*128*128*2);
  float* bcat   = (float*)take((size_t)3*256*4);
  float* gbuf   = (float*)take((size_t)GG*HH*4);
  float* qkvb   = (float*)take((size_t)GG*384*4);
  float* qkvb2  = (float*)take((size_t)GG*384*4);

  dim3 b256(256);
  k_prep<<<dim3(21312), b256, 0, stream>>>(edge_w1, edge_w2, node_w1, node_w2,
    edge_b1, x, emb_w, emb_b, wcatT, w2T, nw1T, nw2T, bcat, h, h_bf, cnt);
  k_hist<<<dim3(EE/256), b256, 0, stream>>>(ei + EE, cnt);
  k_scan<<<dim3(1), dim3(1024), 0, stream>>>(cnt, cursor, NN);
  k_scatter<<<dim3(EE/256), b256, 0, stream>>>(ei, pos, cursor, rec);

  for (int l=0;l<3;++l){
    k_gemm<128,128,0,true,true,false,true,false,true><<<dim3(313,4), b256, 0, stream>>>(
      h_bf, nullptr, wcatT + (size_t)l*256*128, bcat + (size_t)l*256, nullptr, P, nullptr, 256, aggr);
    k_edge<<<dim3(EE/128), dim3(512), 0, stream>>>(P, w2T + (size_t)l*128*128,
      edge_w1 + ((size_t)l*257 + 256)*128, edge_b2 + (size_t)l*128, rec, aggr);
    k_gemm<256,128,1,true,true,false,true,false,false><<<dim3(313,2), b256, 0, stream>>>(
      h_bf, aggr, nw1T + (size_t)l*128*256, node_b1 + (size_t)l*128, nullptr, u1, nullptr, 128, nullptr);
    k_gemm<128,128,0,true,true,true,true,true,false><<<dim3(313,2), b256, 0, stream>>>(
      u1, nullptr, nw2T + (size_t)l*128*128, node_b2 + (size_t)l*128, h, h_bf, h, 128, nullptr);
  }

  k_pool_qkv<<<dim3(GG), dim3(384), 0, stream>>>(h, batch, qkv_w, qkv_b, gbuf, qkvb);
  k_tail<0><<<dim3(GG), dim3(128), 0, stream>>>(qkvb, out_w, out_b,
    ln1_g, ln1_b, ff_w1, ff_b1, ff_w2, ff_b2, ln2_g, ln2_b, gbuf,
    qkv_w + (size_t)128*384, qkv_b + 384, qkvb2,
    nullptr, nullptr, nullptr, nullptr, nullptr);
  k_tail<1><<<dim3(GG), dim3(128), 0, stream>>>(qkvb2, out_w + (size_t)128*128, out_b + 128,
    ln1_g + 128, ln1_b + 128, ff_w1 + (size_t)128*256, ff_b1 + 256,
    ff_w2 + (size_t)256*128, ff_b2 + 128, ln2_g + 128, ln2_b + 128, gbuf,
    nullptr, nullptr, nullptr,
    cls_w1, cls_b1, cls_w2, cls_b2, out);
}

// Round 6
// 669.060 us; speedup vs baseline: 1.5731x; 1.0867x over previous
//
#include <hip/hip_runtime.h>
#include <hip/hip_bf16.h>
#include <stdint.h>

#define NN 40000
#define EE 640000
#define GG 256
#define FFE 9
#define HH 128

typedef __bf16 bf16;
typedef __bf16 bf16x8 __attribute__((ext_vector_type(8)));
typedef float f32x4 __attribute__((ext_vector_type(4)));

__device__ __forceinline__ f32x4 mfma16(bf16x8 a, bf16x8 b, f32x4 c){
  return __builtin_amdgcn_mfma_f32_16x16x32_bf16(a, b, c, 0, 0, 0);
}
__device__ __forceinline__ float silu_f(float x){
  return x * __builtin_amdgcn_rcpf(1.0f + __expf(-x));
}
__device__ __forceinline__ uint16_t bfb(float x){ bf16 h=(bf16)x; return *(uint16_t*)&h; }
// byte-offset XOR swizzle for [row][256B] LDS tiles
__device__ __forceinline__ int swz(int row, int cb){
  return row*256 + (cb ^ ((row & 7) << 4));
}

// ---------------- merged prep ----------------
__global__ __launch_bounds__(256) void k_prep(
    const float* __restrict__ edge_w1, const float* __restrict__ edge_w2,
    const float* __restrict__ node_w1, const float* __restrict__ node_w2,
    const float* __restrict__ edge_b1,
    const float* __restrict__ x, const float* __restrict__ emb_w,
    const float* __restrict__ emb_b,
    bf16* __restrict__ wcatT, bf16* __restrict__ w2T,
    bf16* __restrict__ nw1T, bf16* __restrict__ nw2T,
    float* __restrict__ bcat, float* __restrict__ h,
    int* __restrict__ cnt)
{
  int b = blockIdx.x, tid = threadIdx.x;
  if (b < 192){
    int l = b/64; int t2 = (b%64)*256 + tid;
    int n = t2 >> 7, k = t2 & 127;
    wcatT[(size_t)l*32768 + n*128 + k] = (bf16)edge_w1[(size_t)l*32896 + k*128 + n];
  } else if (b < 384){
    int lb = b - 192; int l = lb/64; int t2 = (lb%64)*256 + tid;
    int n = t2 >> 7, k = t2 & 127;
    wcatT[(size_t)l*32768 + 16384 + n*128 + k] = (bf16)edge_w1[(size_t)l*32896 + (128+k)*128 + n];
  } else if (b < 576){
    int lb = b - 384; int l = lb/64; int t2 = (lb%64)*256 + tid;
    int n = t2 >> 7, k = t2 & 127;
    w2T[(size_t)l*16384 + n*128 + k] = (bf16)edge_w2[(size_t)l*16384 + k*128 + n];
  } else if (b < 960){
    int lb = b - 576; int l = lb/128; int t2 = (lb%128)*256 + tid;
    int n = t2 >> 8, k = t2 & 255;
    nw1T[(size_t)l*32768 + n*256 + k] = (bf16)node_w1[(size_t)l*32768 + k*128 + n];
  } else if (b < 1152){
    int lb = b - 960; int l = lb/64; int t2 = (lb%64)*256 + tid;
    int n = t2 >> 7, k = t2 & 127;
    nw2T[(size_t)l*16384 + n*128 + k] = (bf16)node_w2[(size_t)l*16384 + k*128 + n];
  } else if (b < 1155){
    int l = b - 1152;
    bcat[l*256 + tid] = (tid < 128) ? edge_b1[l*128 + tid] : 0.0f;
  } else if (b < 1312){
    int i = (b - 1155)*256 + tid;
    if (i < NN) cnt[i] = 0;
  } else {
    int idx = (b - 1312)*256 + tid;
    int n = idx >> 7, f = idx & 127;
    float s = emb_b[f];
    const float* xr = x + n*FFE;
    #pragma unroll
    for (int k=0;k<FFE;++k) s += xr[k]*emb_w[k*HH + f];
    h[idx] = s;
  }
}

// ---------------- counting sort by dst ----------------
__global__ __launch_bounds__(256) void k_hist(const int* __restrict__ dst, int* __restrict__ cnt){
  int e = blockIdx.x*256 + threadIdx.x;
  if (e < EE) atomicAdd(&cnt[dst[e]], 1);
}

__global__ __launch_bounds__(1024) void k_scan(const int* __restrict__ cnt, int* __restrict__ cursor, int n){
  __shared__ int s_wsum[16];
  __shared__ int s_run;
  int tid = threadIdx.x, lane = tid & 63, wv = tid >> 6;
  if (tid == 0) s_run = 0;
  __syncthreads();
  for (int base=0; base<n; base+=4096){
    int i = base + tid*4;
    int c0 = (i  <n)? cnt[i  ] : 0;
    int c1 = (i+1<n)? cnt[i+1] : 0;
    int c2 = (i+2<n)? cnt[i+2] : 0;
    int c3 = (i+3<n)? cnt[i+3] : 0;
    int t0 = c0, t1 = t0+c1, t2 = t1+c2, t3 = t2+c3;
    int xx = t3;
    #pragma unroll
    for (int off=1; off<64; off<<=1){ int t = __shfl_up(xx, off); if (lane>=off) xx += t; }
    if (lane==63) s_wsum[wv] = xx;
    __syncthreads();
    if (wv==0 && lane<16){
      int y = s_wsum[lane];
      #pragma unroll
      for (int off=1; off<16; off<<=1){ int t = __shfl_up(y, off, 16); if (lane>=off) y += t; }
      s_wsum[lane] = y;
    }
    __syncthreads();
    int woff = wv ? s_wsum[wv-1] : 0;
    int run = s_run;
    int eb = run + woff + xx - t3;
    if (i  <n) cursor[i  ] = eb;
    if (i+1<n) cursor[i+1] = eb + t0;
    if (i+2<n) cursor[i+2] = eb + t1;
    if (i+3<n) cursor[i+3] = eb + t2;
    __syncthreads();
    if (tid==0) s_run = run + s_wsum[15];
    __syncthreads();
  }
}

__global__ __launch_bounds__(256) void k_scatter(
    const int* __restrict__ ei, const float* __restrict__ pos,
    int* __restrict__ cursor, int4* __restrict__ rec)
{
  int e = blockIdx.x*256 + threadIdx.x;
  if (e >= EE) return;
  int s = ei[e], d = ei[EE + e];
  int p = atomicAdd(&cursor[d], 1);
  float dx = pos[d*3+0]-pos[s*3+0];
  float dy = pos[d*3+1]-pos[s*3+1];
  float dz = pos[d*3+2]-pos[s*3+2];
  int4 rc; rc.x = s; rc.y = d; rc.z = __float_as_int(sqrtf(dx*dx+dy*dy+dz*dz)); rc.w = 0;
  rec[p] = rc;
}

// ---------------- 128x64-tile bf16 MFMA GEMM (initial P only) ----------------
template<int KTOT, int K1, int ACT, bool A1BF, bool BIAS, bool RESID, bool OBF, bool OF, bool ZAGGR>
__global__ __launch_bounds__(256) void k_gemm(
    const void* __restrict__ a1v, const float* __restrict__ a2,
    const bf16* __restrict__ wt, const float* __restrict__ bias,
    const float* __restrict__ resid, bf16* __restrict__ outb,
    float* __restrict__ outf, int Nw, float* __restrict__ aggr)
{
  constexpr int LDK = 136;
  __shared__ bf16 s_a[128*LDK];
  __shared__ bf16 s_w[64*LDK];
  int tid = threadIdx.x, lane = tid & 63, w = tid >> 6;
  int m0 = blockIdx.x*128, n0 = blockIdx.y*64;
  if (ZAGGR && blockIdx.y == 0){
    int nrows = NN - m0; if (nrows > 128) nrows = 128;
    f32x4 z = {0.f,0.f,0.f,0.f};
    for (int i = tid; i < nrows*32; i += 256)
      *(f32x4*)(aggr + (size_t)m0*128 + (size_t)i*4) = z;
  }
  f32x4 acc[2][4];
  #pragma unroll
  for (int i=0;i<2;++i)
    #pragma unroll
    for (int j=0;j<4;++j)
      #pragma unroll
      for (int r=0;r<4;++r) acc[i][j][r]=0.f;
  int rsel = lane & 15, ksel = (lane>>4)*8;
  int wm = w*32;

  for (int kh=0; kh<KTOT; kh+=128){
    #pragma unroll
    for (int it=0; it<8; ++it){
      int idx = tid + it*256;
      int row = idx >> 4, col = (idx & 15)*8;
      int gc = kh + col;
      int grow = m0 + row; if (grow > NN-1) grow = NN-1;
      bf16x8 vv;
      if (gc < K1){
        if (A1BF){
          vv = *(const bf16x8*)((const bf16*)a1v + (size_t)grow*K1 + gc);
        } else {
          const float* srcp = (const float*)a1v + (size_t)grow*K1 + gc;
          f32x4 u0 = *(const f32x4*)srcp;
          f32x4 u1 = *(const f32x4*)(srcp+4);
          vv[0]=(bf16)u0[0]; vv[1]=(bf16)u0[1]; vv[2]=(bf16)u0[2]; vv[3]=(bf16)u0[3];
          vv[4]=(bf16)u1[0]; vv[5]=(bf16)u1[1]; vv[6]=(bf16)u1[2]; vv[7]=(bf16)u1[3];
        }
      } else {
        const float* srcp = a2 + (size_t)grow*(KTOT-K1) + (gc-K1);
        f32x4 u0 = *(const f32x4*)srcp;
        f32x4 u1 = *(const f32x4*)(srcp+4);
        vv[0]=(bf16)u0[0]; vv[1]=(bf16)u0[1]; vv[2]=(bf16)u0[2]; vv[3]=(bf16)u0[3];
        vv[4]=(bf16)u1[0]; vv[5]=(bf16)u1[1]; vv[6]=(bf16)u1[2]; vv[7]=(bf16)u1[3];
      }
      *(bf16x8*)&s_a[row*LDK + col] = vv;
    }
    #pragma unroll
    for (int it=0; it<4; ++it){
      int idx = tid + it*256;
      int row = idx >> 4, col = (idx & 15)*8;
      *(bf16x8*)&s_w[row*LDK + col] = *(const bf16x8*)(wt + (size_t)(n0+row)*KTOT + kh + col);
    }
    __syncthreads();
    #pragma unroll
    for (int ks=0; ks<4; ++ks){
      int kb = ks*32 + ksel;
      bf16x8 fa0 = *(const bf16x8*)&s_a[(wm+rsel)*LDK + kb];
      bf16x8 fa1 = *(const bf16x8*)&s_a[(wm+16+rsel)*LDK + kb];
      #pragma unroll
      for (int j=0;j<4;++j){
        bf16x8 fb = *(const bf16x8*)&s_w[(j*16+rsel)*LDK + kb];
        acc[0][j]=mfma16(fa0,fb,acc[0][j]);
        acc[1][j]=mfma16(fa1,fb,acc[1][j]);
      }
    }
    __syncthreads();
  }

  #pragma unroll
  for (int i=0;i<2;++i){
    #pragma unroll
    for (int j=0;j<4;++j){
      int col = n0 + j*16 + rsel;
      float bv = BIAS ? bias[col] : 0.0f;
      #pragma unroll
      for (int r=0;r<4;++r){
        int row = m0 + wm + i*16 + 4*(lane>>4) + r;
        if (row < NN){
          float v = acc[i][j][r] + bv;
          if (ACT==1) v = silu_f(v);
          if (RESID) v += resid[(size_t)row*Nw + col];
          if (OBF) outb[(size_t)row*Nw + col] = (bf16)v;
          if (OF)  outf[(size_t)row*Nw + col] = v;
        }
      }
    }
  }
}

// ---------------- fused node MLP: u1 -> h update -> next-layer P (+aggr zero) --------
// 64-row tile, 256 threads, 625 blocks. Swapped-operand MFMA (weights as A) so each
// lane holds 4 consecutive output cols -> packed stores. All GEMMs K-staged by 64.
template<bool DOP>
__global__ __launch_bounds__(256) void k_node(
    float* h, float* aggr,
    const bf16* __restrict__ nw1t,  // [128][256]
    const bf16* __restrict__ nw2t,  // [128][128]
    const bf16* __restrict__ wct,   // [256][128] (next layer)
    const float* __restrict__ nb1, const float* __restrict__ nb2,
    const float* __restrict__ bcv,  // [256] (next layer)
    bf16* __restrict__ P)
{
  __shared__ bf16 SA[64][132];   // A1 k-quarter stage; later SH (hnew bf16)
  __shared__ bf16 SW[128][72];   // weight k-quarter stage
  __shared__ bf16 SU[64][132];   // u1 [row][128]
  int tid = threadIdx.x, lane = tid & 63, w = tid >> 6;
  int rsel = lane & 15, hi = lane >> 4;
  int m0 = blockIdx.x * 64;
  int urow = w*16 + rsel;          // this lane's output row within tile
  int grow = m0 + urow;

  f32x4 acc[8];
  #pragma unroll
  for (int nt=0;nt<8;++nt)
    #pragma unroll
    for (int r=0;r<4;++r) acc[nt][r]=0.f;

  // ---- GEMM1: u1' = nw1T @ [h|aggr]^T   (C'[n][row]) ----
  for (int kq=0; kq<4; ++kq){
    const float* src = (kq < 2) ? (h + (size_t)m0*128 + kq*64)
                                : (aggr + (size_t)m0*128 + (kq-2)*64);
    #pragma unroll
    for (int it=0; it<2; ++it){
      int g = tid + it*256;
      int row = g >> 3, cg = (g & 7)*8;
      const float* sp = src + (size_t)row*128 + cg;
      f32x4 u0 = *(const f32x4*)sp, u1v = *(const f32x4*)(sp+4);
      bf16x8 vv;
      vv[0]=(bf16)u0[0]; vv[1]=(bf16)u0[1]; vv[2]=(bf16)u0[2]; vv[3]=(bf16)u0[3];
      vv[4]=(bf16)u1v[0]; vv[5]=(bf16)u1v[1]; vv[6]=(bf16)u1v[2]; vv[7]=(bf16)u1v[3];
      *(bf16x8*)&SA[row][cg] = vv;
    }
    #pragma unroll
    for (int it=0; it<4; ++it){
      int g = tid + it*256;
      int row = g >> 3, cg = (g & 7)*8;
      *(bf16x8*)&SW[row][cg] = *(const bf16x8*)(nw1t + (size_t)row*256 + kq*64 + cg);
    }
    __syncthreads();
    #pragma unroll
    for (int ks=0; ks<2; ++ks){
      int kb = ks*32 + hi*8;
      bf16x8 fa = *(const bf16x8*)&SA[w*16 + rsel][kb];
      #pragma unroll
      for (int nt=0;nt<8;++nt){
        bf16x8 fw = *(const bf16x8*)&SW[nt*16 + rsel][kb];
        acc[nt] = mfma16(fw, fa, acc[nt]);   // A=weights -> C'[n][urow]
      }
    }
    __syncthreads();
  }

  // ---- u1 = silu(acc + b1) -> SU[urow][n], packed 8B stores ----
  #pragma unroll
  for (int nt=0;nt<8;++nt){
    int nb = nt*16 + 4*hi;
    f32x4 b4 = *(const f32x4*)(nb1 + nb);
    uint16_t q0 = bfb(silu_f(acc[nt][0] + b4[0]));
    uint16_t q1 = bfb(silu_f(acc[nt][1] + b4[1]));
    uint16_t q2 = bfb(silu_f(acc[nt][2] + b4[2]));
    uint16_t q3 = bfb(silu_f(acc[nt][3] + b4[3]));
    uint2 pk; pk.x = (unsigned)q0 | ((unsigned)q1 << 16); pk.y = (unsigned)q2 | ((unsigned)q3 << 16);
    *(uint2*)&SU[urow][nb] = pk;
  }
  __syncthreads();

  // ---- GEMM2: hdelta' = nw2T @ u1^T ----
  #pragma unroll
  for (int nt=0;nt<8;++nt)
    #pragma unroll
    for (int r=0;r<4;++r) acc[nt][r]=0.f;
  for (int kq=0; kq<2; ++kq){
    #pragma unroll
    for (int it=0; it<4; ++it){
      int g = tid + it*256;
      int row = g >> 3, cg = (g & 7)*8;
      *(bf16x8*)&SW[row][cg] = *(const bf16x8*)(nw2t + (size_t)row*128 + kq*64 + cg);
    }
    __syncthreads();
    #pragma unroll
    for (int ks=0; ks<2; ++ks){
      int kb = ks*32 + hi*8;
      bf16x8 fa = *(const bf16x8*)&SU[w*16 + rsel][kq*64 + kb];
      #pragma unroll
      for (int nt=0;nt<8;++nt){
        bf16x8 fw = *(const bf16x8*)&SW[nt*16 + rsel][kb];
        acc[nt] = mfma16(fw, fa, acc[nt]);
      }
    }
    __syncthreads();
  }

  // ---- hnew = h + acc + b2 ; write h (f32) + SH (bf16, aliased on SA) ----
  #pragma unroll
  for (int nt=0;nt<8;++nt){
    int nb = nt*16 + 4*hi;
    f32x4 b4 = *(const f32x4*)(nb2 + nb);
    f32x4 h4 = *(const f32x4*)(h + (size_t)grow*128 + nb);
    f32x4 v;
    #pragma unroll
    for (int r=0;r<4;++r) v[r] = h4[r] + acc[nt][r] + b4[r];
    *(f32x4*)(h + (size_t)grow*128 + nb) = v;
    uint2 pk;
    pk.x = (unsigned)bfb(v[0]) | ((unsigned)bfb(v[1]) << 16);
    pk.y = (unsigned)bfb(v[2]) | ((unsigned)bfb(v[3]) << 16);
    *(uint2*)&SA[urow][nb] = pk;
  }
  __syncthreads();

  if (DOP){
    // ---- GEMM3: P' = wcatT @ hnew^T, two n-halves of 128 ----
    for (int nh=0; nh<2; ++nh){
      #pragma unroll
      for (int nt=0;nt<8;++nt)
        #pragma unroll
        for (int r=0;r<4;++r) acc[nt][r]=0.f;
      for (int kq=0; kq<2; ++kq){
        #pragma unroll
        for (int it=0; it<4; ++it){
          int g = tid + it*256;
          int row = g >> 3, cg = (g & 7)*8;
          *(bf16x8*)&SW[row][cg] = *(const bf16x8*)(wct + (size_t)(nh*128+row)*128 + kq*64 + cg);
        }
        __syncthreads();
        #pragma unroll
        for (int ks=0; ks<2; ++ks){
          int kb = ks*32 + hi*8;
          bf16x8 fa = *(const bf16x8*)&SA[w*16 + rsel][kq*64 + kb];
          #pragma unroll
          for (int nt=0;nt<8;++nt){
            bf16x8 fw = *(const bf16x8*)&SW[nt*16 + rsel][kb];
            acc[nt] = mfma16(fw, fa, acc[nt]);
          }
        }
        __syncthreads();
      }
      #pragma unroll
      for (int nt=0;nt<8;++nt){
        int nb = nh*128 + nt*16 + 4*hi;
        f32x4 b4 = *(const f32x4*)(bcv + nb);
        uint2 pk;
        pk.x = (unsigned)bfb(acc[nt][0] + b4[0]) | ((unsigned)bfb(acc[nt][1] + b4[1]) << 16);
        pk.y = (unsigned)bfb(acc[nt][2] + b4[2]) | ((unsigned)bfb(acc[nt][3] + b4[3]) << 16);
        *(uint2*)(P + (size_t)grow*256 + nb) = pk;
      }
    }
    // ---- zero aggr rows for next layer ----
    f32x4 z = {0.f,0.f,0.f,0.f};
    #pragma unroll
    for (int it=0; it<8; ++it){
      int idx = tid + it*256;
      *(f32x4*)(aggr + (size_t)m0*128 + (size_t)idx*4) = z;
    }
  }
}

// ---------------- fused edge MLP + MFMA-based segmented aggregation ----------------
__global__ __launch_bounds__(512, 6) void k_edge(
    const bf16* __restrict__ P, const bf16* __restrict__ w2t,
    const float* __restrict__ w1r, const float* __restrict__ b2,
    const int4* __restrict__ rec, float* __restrict__ aggr)
{
  __shared__ char smem[32768];      // m1 [128 e][256B] swz -> m2t [128 col][256B] swz
  __shared__ int s_dst[128];
  __shared__ unsigned s_segidw[32]; // 128 segids packed u8
  __shared__ int s_segdst[128];
  __shared__ int s_misc[4];
  int tid = threadIdx.x, lane = tid & 63, w = tid >> 6;
  int rsel = lane & 15, hi = lane >> 4;
  int bid = blockIdx.x;
  int swb = (bid & 7) * (EE/128/8) + (bid >> 3);   // XCD-chunked, 5000%8==0
  int e0 = swb * 128;
  int col = w*16 + rsel;

  bf16x8 fb[4];
  #pragma unroll
  for (int ks=0;ks<4;++ks)
    fb[ks] = *(const bf16x8*)(w2t + (size_t)col*128 + ks*32 + hi*8);

  if (tid == 0){
    s_misc[0] = (e0 == 0) ? -2147483647 : rec[e0-1].y;
    s_misc[1] = (e0 + 128 >= EE) ? -2147483647 : rec[e0+128].y;
  }

  int cq = (tid & 15)*8;
  int er = tid >> 4;
  int4 rc[4];
  #pragma unroll
  for (int it=0; it<4; ++it) rc[it] = rec[e0 + er + it*32];
  uint4 pau[4], pbu[4];
  #pragma unroll
  for (int it=0; it<4; ++it){
    pau[it] = *(const uint4*)(P + ((size_t)rc[it].y << 8) + cq);
    pbu[it] = *(const uint4*)(P + ((size_t)rc[it].x << 8) + 128 + cq);
  }
  if (cq == 0){
    #pragma unroll
    for (int it=0; it<4; ++it) s_dst[er + it*32] = rc[it].y;
  }
  f32x4 wr0 = *(const f32x4*)(w1r + cq);
  f32x4 wr1 = *(const f32x4*)(w1r + cq + 4);
  #pragma unroll
  for (int it=0; it<4; ++it){
    float dist = __int_as_float(rc[it].z);
    bf16x8 mm;
    #pragma unroll
    for (int j=0;j<4;++j){
      unsigned ua = ((const unsigned*)&pau[it])[j];
      unsigned ub = ((const unsigned*)&pbu[it])[j];
      float al = __uint_as_float(ua << 16);
      float ah = __uint_as_float(ua & 0xFFFF0000u);
      float bl = __uint_as_float(ub << 16);
      float bh = __uint_as_float(ub & 0xFFFF0000u);
      float wlo = (j<2) ? wr0[2*j]   : wr1[2*(j-2)];
      float whi = (j<2) ? wr0[2*j+1] : wr1[2*(j-2)+1];
      mm[2*j]   = (bf16)silu_f(al + bl + dist*wlo);
      mm[2*j+1] = (bf16)silu_f(ah + bh + dist*whi);
    }
    *(bf16x8*)(smem + swz(er + it*32, cq*2)) = mm;
  }
  __syncthreads();

  if (w == 0){
    int d0 = s_dst[2*lane], d1 = s_dst[2*lane+1];
    int dm1 = (lane == 0) ? 0 : s_dst[2*lane-1];
    int h0 = (lane == 0) ? 1 : (d0 != dm1);
    int h1 = (d1 != d0);
    int p = h0 + h1, x = p;
    #pragma unroll
    for (int off=1; off<64; off<<=1){ int t = __shfl_up(x, off); if (lane>=off) x += t; }
    int excl = x - p;
    int id0 = excl + h0 - 1;
    int id1 = excl + p - 1;
    uint8_t* sb = (uint8_t*)s_segidw;
    sb[2*lane]   = (uint8_t)id0;
    sb[2*lane+1] = (uint8_t)id1;
    if (h0) s_segdst[id0] = d0;
    if (h1) s_segdst[id1] = d1;
    if (lane == 63) s_misc[2] = id1 + 1;
  }

  f32x4 acc[8];
  #pragma unroll
  for (int mt=0;mt<8;++mt)
    #pragma unroll
    for (int r=0;r<4;++r) acc[mt][r]=0.f;
  #pragma unroll
  for (int mt=0;mt<8;++mt){
    #pragma unroll
    for (int ks=0;ks<4;++ks){
      bf16x8 fa = *(const bf16x8*)(smem + swz(mt*16 + rsel, ks*64 + hi*16));
      acc[mt] = mfma16(fa, fb[ks], acc[mt]);
    }
  }
  __syncthreads();

  float bb = b2[col];
  #pragma unroll
  for (int mt=0;mt<8;++mt){
    uint2 pk;
    pk.x = (unsigned)bfb(silu_f(acc[mt][0] + bb)) | ((unsigned)bfb(silu_f(acc[mt][1] + bb)) << 16);
    pk.y = (unsigned)bfb(silu_f(acc[mt][2] + bb)) | ((unsigned)bfb(silu_f(acc[mt][3] + bb)) << 16);
    *(uint2*)(smem + col*256 + ((mt*32 + hi*8) ^ ((col & 7) << 4))) = pk;
  }
  __syncthreads();

  bf16x8 gb[4];
  #pragma unroll
  for (int ks=0;ks<4;++ks)
    gb[ks] = *(const bf16x8*)(smem + col*256 + ((ks*64 + hi*16) ^ ((col & 7) << 4)));
  int nseg = s_misc[2];
  bool openL = (s_dst[0]   == s_misc[0]);
  bool openR = (s_dst[127] == s_misc[1]);
  for (int st = 0; st < nseg; st += 16){
    unsigned tgt = (unsigned)(st + rsel);
    f32x4 racc = {0.f,0.f,0.f,0.f};
    #pragma unroll
    for (int ks=0;ks<4;++ks){
      unsigned w0 = s_segidw[ks*8 + hi*2];
      unsigned w1 = s_segidw[ks*8 + hi*2 + 1];
      union { uint16_t u[8]; bf16x8 v; } sa;
      #pragma unroll
      for (int j=0;j<4;++j){
        sa.u[j]   = (((w0 >> (8*j)) & 255u) == tgt) ? (uint16_t)0x3F80 : (uint16_t)0;
        sa.u[4+j] = (((w1 >> (8*j)) & 255u) == tgt) ? (uint16_t)0x3F80 : (uint16_t)0;
      }
      racc = mfma16(sa.v, gb[ks], racc);
    }
    #pragma unroll
    for (int r=0;r<4;++r){
      int s = st + 4*hi + r;
      if (s < nseg){
        float v = racc[r];
        size_t off = (size_t)s_segdst[s]*128 + col;
        bool atom = (s == 0 && openL) || (s == nseg-1 && openR);
        if (atom) atomicAdd(&aggr[off], v);
        else      aggr[off] = v;
      }
    }
  }
}

// ---------------- pooling + transformer (fp32) ----------------
__device__ __forceinline__ int lbound(const int* a, int n, int key){
  int lo=0, hi=n;
  while (lo<hi){ int mid=(lo+hi)>>1; if (a[mid]<key) lo=mid+1; else hi=mid; }
  return lo;
}

__global__ __launch_bounds__(384) void k_pool_qkv(
    const float* __restrict__ h, const int* __restrict__ batch,
    const float* __restrict__ wq, const float* __restrict__ bq,
    float* __restrict__ gbuf, float* __restrict__ qkvb)
{
  __shared__ float sg[128];
  int gr = blockIdx.x, tid = threadIdx.x;
  if (tid < 128){
    int lo = lbound(batch, NN, gr), hi2 = lbound(batch, NN, gr+1);
    float s = 0.f;
    for (int n=lo;n<hi2;++n) s += h[(size_t)n*HH + tid];
    int c = hi2 - lo; if (c < 1) c = 1;
    s /= (float)c;
    sg[tid] = s; gbuf[gr*128 + tid] = s;
  }
  __syncthreads();
  float a = bq[tid];
  for (int k=0;k<128;++k) a += sg[k]*wq[k*384 + tid];
  qkvb[gr*384 + tid] = a;
}

template<int MODE>
__global__ __launch_bounds__(128) void k_tail(
    const float* __restrict__ qkv, const float* __restrict__ wo,
    const float* __restrict__ bo, const float* __restrict__ l1g,
    const float* __restrict__ l1b, const float* __restrict__ w1,
    const float* __restrict__ b1f, const float* __restrict__ w2,
    const float* __restrict__ b2f, const float* __restrict__ l2g,
    const float* __restrict__ l2b, float* __restrict__ gbuf,
    const float* __restrict__ wq2, const float* __restrict__ bq2,
    float* __restrict__ qkvb2,
    const float* __restrict__ cw1, const float* __restrict__ cb1,
    const float* __restrict__ cw2, const float* __restrict__ cb2,
    float* __restrict__ out)
{
  __shared__ float sq[128];
  __shared__ float ss[4][256];
  __shared__ float so[128];
  __shared__ float st[256];
  __shared__ float red[4];
  int r = blockIdx.x, tid = threadIdx.x;
  sq[tid] = qkv[r*384 + tid];
  __syncthreads();
  const float scale = 0.17677669529663687f;
  for (int i=tid; i<1024; i+=128){
    int hh = i >> 8, j = i & 255;
    const float* kr = qkv + j*384 + 128 + hh*32;
    const float* qr = sq + hh*32;
    float s=0;
    #pragma unroll
    for (int d=0;d<32;++d) s += qr[d]*kr[d];
    ss[hh][j] = s*scale;
  }
  __syncthreads();
  int hh = tid >> 5, sl = tid & 31;
  float m = -1e30f;
  #pragma unroll
  for (int q8=0;q8<8;++q8) m = fmaxf(m, ss[hh][sl + q8*32]);
  #pragma unroll
  for (int off=16; off; off>>=1) m = fmaxf(m, __shfl_xor(m, off, 32));
  float sum = 0.f;
  #pragma unroll
  for (int q8=0;q8<8;++q8){
    float e = __expf(ss[hh][sl+q8*32] - m);
    ss[hh][sl+q8*32] = e;
    sum += e;
  }
  #pragma unroll
  for (int off=16; off; off>>=1) sum += __shfl_xor(sum, off, 32);
  float inv = __builtin_amdgcn_rcpf(sum);
  __syncthreads();
  float accv = 0.f;
  for (int j=0;j<256;++j) accv += ss[hh][j]*qkv[j*384 + 256 + hh*32 + sl];
  so[tid] = accv*inv;
  __syncthreads();
  float a = bo[tid];
  for (int k=0;k<128;++k) a += so[k]*wo[k*128 + tid];
  float val = gbuf[r*128 + tid] + a;
  {
    float s = val, q = val*val;
    #pragma unroll
    for (int off=32; off; off>>=1){ s += __shfl_xor(s, off); q += __shfl_xor(q, off); }
    int lane = tid & 63, wv = tid >> 6;
    if (lane==0){ red[wv*2]=s; red[wv*2+1]=q; }
    __syncthreads();
    float S = red[0]+red[2], Q = red[1]+red[3];
    float mean = S*(1.0f/128.0f);
    float var = Q*(1.0f/128.0f) - mean*mean;
    float ninv = rsqrtf(var + 1e-5f);
    val = (val-mean)*ninv*l1g[tid] + l1b[tid];
  }
  sq[tid] = val;
  __syncthreads();
  float a0 = b1f[tid], a1 = b1f[tid+128];
  for (int k=0;k<128;++k){
    float gv = sq[k];
    a0 += gv*w1[k*256 + tid];
    a1 += gv*w1[k*256 + tid + 128];
  }
  st[tid]     = fmaxf(a0, 0.f);
  st[tid+128] = fmaxf(a1, 0.f);
  __syncthreads();
  float b = b2f[tid];
  for (int k=0;k<256;++k) b += st[k]*w2[k*128 + tid];
  float val2 = val + b;
  {
    float s = val2, q = val2*val2;
    #pragma unroll
    for (int off=32; off; off>>=1){ s += __shfl_xor(s, off); q += __shfl_xor(q, off); }
    int lane = tid & 63, wv = tid >> 6;
    __syncthreads();
    if (lane==0){ red[wv*2]=s; red[wv*2+1]=q; }
    __syncthreads();
    float S = red[0]+red[2], Q = red[1]+red[3];
    float mean = S*(1.0f/128.0f);
    float var = Q*(1.0f/128.0f) - mean*mean;
    float ninv = rsqrtf(var + 1e-5f);
    val2 = (val2-mean)*ninv*l2g[tid] + l2b[tid];
  }
  gbuf[r*128 + tid] = val2;
  if (MODE == 0){
    sq[tid] = val2;
    __syncthreads();
    float q0 = bq2[tid], q1 = bq2[tid+128], q2 = bq2[tid+256];
    for (int k=0;k<128;++k){
      float gv = sq[k];
      const float* wr = wq2 + k*384;
      q0 += gv*wr[tid]; q1 += gv*wr[tid+128]; q2 += gv*wr[tid+256];
    }
    qkvb2[r*384+tid]=q0; qkvb2[r*384+tid+128]=q1; qkvb2[r*384+tid+256]=q2;
  }
  if (MODE == 1){
    so[tid] = val2;
    __syncthreads();
    if (tid < 64){
      float c = cb1[tid];
      for (int k=0;k<128;++k) c += so[k]*cw1[k*64 + tid];
      c = fmaxf(c, 0.f);
      float p = c * cw2[tid];
      #pragma unroll
      for (int off=32; off; off>>=1) p += __shfl_xor(p, off);
      if (tid==0) out[r] = p + cb2[0];
    }
  }
}

// ---------------- launch ----------------
extern "C" void kernel_launch(void* const* d_in, const int* in_sizes, int n_in,
                              void* d_out, int out_size, void* d_ws, size_t ws_size,
                              hipStream_t stream)
{
  (void)in_sizes; (void)n_in; (void)out_size; (void)ws_size;
  const float* x      = (const float*)d_in[0];
  const float* pos    = (const float*)d_in[1];
  const float* emb_w  = (const float*)d_in[2];
  const float* emb_b  = (const float*)d_in[3];
  const float* edge_w1= (const float*)d_in[4];
  const float* edge_b1= (const float*)d_in[5];
  const float* edge_w2= (const float*)d_in[6];
  const float* edge_b2= (const float*)d_in[7];
  const float* node_w1= (const float*)d_in[8];
  const float* node_b1= (const float*)d_in[9];
  const float* node_w2= (const float*)d_in[10];
  const float* node_b2= (const float*)d_in[11];
  const float* qkv_w  = (const float*)d_in[12];
  const float* qkv_b  = (const float*)d_in[13];
  const float* out_w  = (const float*)d_in[14];
  const float* out_b  = (const float*)d_in[15];
  const float* ln1_g  = (const float*)d_in[16];
  const float* ln1_b  = (const float*)d_in[17];
  const float* ln2_g  = (const float*)d_in[18];
  const float* ln2_b  = (const float*)d_in[19];
  const float* ff_w1  = (const float*)d_in[20];
  const float* ff_b1  = (const float*)d_in[21];
  const float* ff_w2  = (const float*)d_in[22];
  const float* ff_b2  = (const float*)d_in[23];
  const float* cls_w1 = (const float*)d_in[24];
  const float* cls_b1 = (const float*)d_in[25];
  const float* cls_w2 = (const float*)d_in[26];
  const float* cls_b2 = (const float*)d_in[27];
  const int* ei       = (const int*)d_in[28];
  const int* batch    = (const int*)d_in[29];
  float* out = (float*)d_out;

  uint8_t* wp = (uint8_t*)d_ws;
  auto take = [&](size_t nb)->void*{ void* r = wp; wp += (nb + 255) & ~(size_t)255; return r; };
  float* h      = (float*)take((size_t)NN*HH*4);
  bf16*  P      = (bf16*) take((size_t)NN*256*2);
  float* aggr   = (float*)take((size_t)NN*HH*4);
  int*   cnt    = (int*)  take((size_t)NN*4);
  int*   cursor = (int*)  take((size_t)NN*4);
  int4*  rec    = (int4*) take((size_t)EE*16);
  bf16*  wcatT  = (bf16*) take((size_t)3*256*128*2);
  bf16*  w2T    = (bf16*) take((size_t)3*128*128*2);
  bf16*  nw1T   = (bf16*) take((size_t)3*128*256*2);
  bf16*  nw2T   = (bf16*) take((size_t)3*128*128*2);
  float* bcat   = (float*)take((size_t)3*256*4);
  float* gbuf   = (float*)take((size_t)GG*HH*4);
  float* qkvb   = (float*)take((size_t)GG*384*4);
  float* qkvb2  = (float*)take((size_t)GG*384*4);

  dim3 b256(256);
  k_prep<<<dim3(21312), b256, 0, stream>>>(edge_w1, edge_w2, node_w1, node_w2,
    edge_b1, x, emb_w, emb_b, wcatT, w2T, nw1T, nw2T, bcat, h, cnt);
  k_hist<<<dim3(EE/256), b256, 0, stream>>>(ei + EE, cnt);
  k_scan<<<dim3(1), dim3(1024), 0, stream>>>(cnt, cursor, NN);
  k_scatter<<<dim3(EE/256), b256, 0, stream>>>(ei, pos, cursor, rec);

  // initial P (layer 0) from h, also zeroes aggr
  k_gemm<128,128,0,false,true,false,true,false,true><<<dim3(313,4), b256, 0, stream>>>(
    h, nullptr, wcatT, bcat, nullptr, P, nullptr, 256, aggr);

  for (int l=0;l<3;++l){
    k_edge<<<dim3(EE/128), dim3(512), 0, stream>>>(P, w2T + (size_t)l*16384,
      edge_w1 + ((size_t)l*257 + 256)*128, edge_b2 + (size_t)l*128, rec, aggr);
    if (l < 2){
      k_node<true><<<dim3(625), b256, 0, stream>>>(h, aggr,
        nw1T + (size_t)l*32768, nw2T + (size_t)l*16384, wcatT + (size_t)(l+1)*32768,
        node_b1 + (size_t)l*128, node_b2 + (size_t)l*128, bcat + (size_t)(l+1)*256, P);
    } else {
      k_node<false><<<dim3(625), b256, 0, stream>>>(h, aggr,
        nw1T + (size_t)l*32768, nw2T + (size_t)l*16384, wcatT,
        node_b1 + (size_t)l*128, node_b2 + (size_t)l*128, bcat, P);
    }
  }

  k_pool_qkv<<<dim3(GG), dim3(384), 0, stream>>>(h, batch, qkv_w, qkv_b, gbuf, qkvb);
  k_tail<0><<<dim3(GG), dim3(128), 0, stream>>>(qkvb, out_w, out_b,
    ln1_g, ln1_b, ff_w1, ff_b1, ff_w2, ff_b2, ln2_g, ln2_b, gbuf,
    qkv_w + (size_t)128*384, qkv_b + 384, qkvb2,
    nullptr, nullptr, nullptr, nullptr, nullptr);
  k_tail<1><<<dim3(GG), dim3(128), 0, stream>>>(qkvb2, out_w + (size_t)128*128, out_b + 128,
    ln1_g + 128, ln1_b + 128, ff_w1 + (size_t)128*256, ff_b1 + 256,
    ff_w2 + (size_t)256*128, ff_b2 + 128, ln2_g + 128, ln2_b + 128, gbuf,
    nullptr, nullptr, nullptr,
    cls_w1, cls_b1, cls_w2, cls_b2, out);
}

// Round 7
// 631.320 us; speedup vs baseline: 1.6672x; 1.0598x over previous
//
#include <hip/hip_runtime.h>
#include <hip/hip_bf16.h>
#include <stdint.h>

#define NN 40000
#define EE 640000
#define GG 256
#define FFE 9
#define HH 128

typedef __bf16 bf16;
typedef __bf16 bf16x8 __attribute__((ext_vector_type(8)));
typedef float f32x4 __attribute__((ext_vector_type(4)));

__device__ __forceinline__ f32x4 mfma16(bf16x8 a, bf16x8 b, f32x4 c){
  return __builtin_amdgcn_mfma_f32_16x16x32_bf16(a, b, c, 0, 0, 0);
}
__device__ __forceinline__ float silu_f(float x){
  return x * __builtin_amdgcn_rcpf(1.0f + __expf(-x));
}
__device__ __forceinline__ uint16_t bfb(float x){ bf16 h=(bf16)x; return *(uint16_t*)&h; }
// byte-offset XOR swizzle for [row][256B] LDS tiles
__device__ __forceinline__ int swz(int row, int cb){
  return row*256 + (cb ^ ((row & 7) << 4));
}

// ---------------- merged prep ----------------
__global__ __launch_bounds__(256) void k_prep(
    const float* __restrict__ edge_w1, const float* __restrict__ edge_w2,
    const float* __restrict__ node_w1, const float* __restrict__ node_w2,
    const float* __restrict__ edge_b1,
    const float* __restrict__ x, const float* __restrict__ emb_w,
    const float* __restrict__ emb_b,
    bf16* __restrict__ wcatT, bf16* __restrict__ w2T,
    bf16* __restrict__ nw1T, bf16* __restrict__ nw2T,
    float* __restrict__ bcat, float* __restrict__ h,
    int* __restrict__ cnt)
{
  int b = blockIdx.x, tid = threadIdx.x;
  if (b < 192){
    int l = b/64; int t2 = (b%64)*256 + tid;
    int n = t2 >> 7, k = t2 & 127;
    wcatT[(size_t)l*32768 + n*128 + k] = (bf16)edge_w1[(size_t)l*32896 + k*128 + n];
  } else if (b < 384){
    int lb = b - 192; int l = lb/64; int t2 = (lb%64)*256 + tid;
    int n = t2 >> 7, k = t2 & 127;
    wcatT[(size_t)l*32768 + 16384 + n*128 + k] = (bf16)edge_w1[(size_t)l*32896 + (128+k)*128 + n];
  } else if (b < 576){
    int lb = b - 384; int l = lb/64; int t2 = (lb%64)*256 + tid;
    int n = t2 >> 7, k = t2 & 127;
    w2T[(size_t)l*16384 + n*128 + k] = (bf16)edge_w2[(size_t)l*16384 + k*128 + n];
  } else if (b < 960){
    int lb = b - 576; int l = lb/128; int t2 = (lb%128)*256 + tid;
    int n = t2 >> 8, k = t2 & 255;
    nw1T[(size_t)l*32768 + n*256 + k] = (bf16)node_w1[(size_t)l*32768 + k*128 + n];
  } else if (b < 1152){
    int lb = b - 960; int l = lb/64; int t2 = (lb%64)*256 + tid;
    int n = t2 >> 7, k = t2 & 127;
    nw2T[(size_t)l*16384 + n*128 + k] = (bf16)node_w2[(size_t)l*16384 + k*128 + n];
  } else if (b < 1155){
    int l = b - 1152;
    bcat[l*256 + tid] = (tid < 128) ? edge_b1[l*128 + tid] : 0.0f;
  } else if (b < 1312){
    int i = (b - 1155)*256 + tid;
    if (i < NN) cnt[i] = 0;
  } else {
    int idx = (b - 1312)*256 + tid;
    int n = idx >> 7, f = idx & 127;
    float s = emb_b[f];
    const float* xr = x + n*FFE;
    #pragma unroll
    for (int k=0;k<FFE;++k) s += xr[k]*emb_w[k*HH + f];
    h[idx] = s;
  }
}

// ---------------- counting sort by dst ----------------
__global__ __launch_bounds__(256) void k_hist(const int* __restrict__ dst, int* __restrict__ cnt){
  int e = blockIdx.x*256 + threadIdx.x;
  if (e < EE) atomicAdd(&cnt[dst[e]], 1);
}

// parallel 2-level scan: scanA computes per-4096-chunk local exclusive prefix + chunk total
__global__ __launch_bounds__(1024) void k_scanA(const int* __restrict__ cnt,
    int* __restrict__ cursor, int* __restrict__ partials, int n)
{
  __shared__ int s_wsum[16];
  int tid = threadIdx.x, lane = tid & 63, wv = tid >> 6;
  int i = blockIdx.x*4096 + tid*4;
  int c0 = (i  <n)? cnt[i  ] : 0;
  int c1 = (i+1<n)? cnt[i+1] : 0;
  int c2 = (i+2<n)? cnt[i+2] : 0;
  int c3 = (i+3<n)? cnt[i+3] : 0;
  int t0 = c0, t1 = t0+c1, t2 = t1+c2, t3 = t2+c3;
  int xx = t3;
  #pragma unroll
  for (int off=1; off<64; off<<=1){ int t = __shfl_up(xx, off); if (lane>=off) xx += t; }
  if (lane==63) s_wsum[wv] = xx;
  __syncthreads();
  if (wv==0 && lane<16){
    int y = s_wsum[lane];
    #pragma unroll
    for (int off=1; off<16; off<<=1){ int t = __shfl_up(y, off, 16); if (lane>=off) y += t; }
    s_wsum[lane] = y;
  }
  __syncthreads();
  int woff = wv ? s_wsum[wv-1] : 0;
  int eb = woff + xx - t3;
  if (i  <n) cursor[i  ] = eb;
  if (i+1<n) cursor[i+1] = eb + t0;
  if (i+2<n) cursor[i+2] = eb + t1;
  if (i+3<n) cursor[i+3] = eb + t2;
  if (tid==1023) partials[blockIdx.x] = woff + xx;
}

__global__ __launch_bounds__(64) void k_scanB(int* __restrict__ partials, int nb){
  int lane = threadIdx.x;
  int v = (lane < nb) ? partials[lane] : 0;
  int x = v;
  #pragma unroll
  for (int off=1; off<64; off<<=1){ int t = __shfl_up(x, off); if (lane>=off) x += t; }
  if (lane < nb) partials[lane] = x - v;   // exclusive
}

__global__ __launch_bounds__(256) void k_scatter(
    const int* __restrict__ ei, const float* __restrict__ pos,
    int* __restrict__ cursor, const int* __restrict__ offs, int4* __restrict__ rec)
{
  int e = blockIdx.x*256 + threadIdx.x;
  if (e >= EE) return;
  int s = ei[e], d = ei[EE + e];
  int p = atomicAdd(&cursor[d], 1) + offs[d >> 12];
  float dx = pos[d*3+0]-pos[s*3+0];
  float dy = pos[d*3+1]-pos[s*3+1];
  float dz = pos[d*3+2]-pos[s*3+2];
  int4 rc; rc.x = s; rc.y = d; rc.z = __float_as_int(sqrtf(dx*dx+dy*dy+dz*dz)); rc.w = 0;
  rec[p] = rc;
}

// ---------------- initial P: P = h @ [W1d|W1s] + bcat, fused aggr zero ----------------
__global__ __launch_bounds__(256) void k_pgen(
    const float* __restrict__ h, const bf16* __restrict__ wct,
    const float* __restrict__ bcv, bf16* __restrict__ P, float* __restrict__ aggr)
{
  __shared__ bf16 SA[64][136];
  __shared__ bf16 SW[128][136];
  int tid = threadIdx.x, lane = tid & 63, w = tid >> 6;
  int rsel = lane & 15, hi = lane >> 4;
  int m0 = blockIdx.x * 64;
  // zero aggr rows
  f32x4 z = {0.f,0.f,0.f,0.f};
  #pragma unroll
  for (int it=0; it<8; ++it)
    *(f32x4*)(aggr + (size_t)m0*128 + (size_t)(tid + it*256)*4) = z;
  // stage h tile (f32 -> bf16)
  #pragma unroll
  for (int it=0; it<4; ++it){
    int idx = tid + it*256;
    int row = idx >> 4, cg = (idx & 15)*8;
    const float* sp = h + (size_t)(m0+row)*128 + cg;
    f32x4 u0 = *(const f32x4*)sp, u1v = *(const f32x4*)(sp+4);
    bf16x8 vv;
    vv[0]=(bf16)u0[0]; vv[1]=(bf16)u0[1]; vv[2]=(bf16)u0[2]; vv[3]=(bf16)u0[3];
    vv[4]=(bf16)u1v[0]; vv[5]=(bf16)u1v[1]; vv[6]=(bf16)u1v[2]; vv[7]=(bf16)u1v[3];
    *(bf16x8*)&SA[row][cg] = vv;
  }
  __syncthreads();
  int urow = w*16 + rsel;
  for (int nh=0; nh<2; ++nh){
    #pragma unroll
    for (int it=0; it<8; ++it){
      int idx = tid + it*256;
      int row = idx >> 4, cg = (idx & 15)*8;
      *(bf16x8*)&SW[row][cg] = *(const bf16x8*)(wct + (size_t)(nh*128+row)*128 + cg);
    }
    __syncthreads();
    f32x4 acc[8];
    #pragma unroll
    for (int nt=0;nt<8;++nt)
      #pragma unroll
      for (int r=0;r<4;++r) acc[nt][r]=0.f;
    #pragma unroll
    for (int ks=0; ks<4; ++ks){
      int kb = ks*32 + hi*8;
      bf16x8 fa = *(const bf16x8*)&SA[urow][kb];
      #pragma unroll
      for (int nt=0;nt<8;++nt){
        bf16x8 fw = *(const bf16x8*)&SW[nt*16 + rsel][kb];
        acc[nt] = mfma16(fw, fa, acc[nt]);
      }
    }
    __syncthreads();
    #pragma unroll
    for (int nt=0;nt<8;++nt){
      int nb = nh*128 + nt*16 + 4*hi;
      f32x4 b4 = *(const f32x4*)(bcv + nb);
      uint2 pk;
      pk.x = (unsigned)bfb(acc[nt][0] + b4[0]) | ((unsigned)bfb(acc[nt][1] + b4[1]) << 16);
      pk.y = (unsigned)bfb(acc[nt][2] + b4[2]) | ((unsigned)bfb(acc[nt][3] + b4[3]) << 16);
      *(uint2*)(P + (size_t)(m0+urow)*256 + nb) = pk;
    }
  }
}

// ---------------- fused node MLP: u1 -> h update -> next-layer P (+aggr zero) --------
template<bool DOP>
__global__ __launch_bounds__(256) void k_node(
    float* h, float* aggr,
    const bf16* __restrict__ nw1t,  // [128][256]
    const bf16* __restrict__ nw2t,  // [128][128]
    const bf16* __restrict__ wct,   // [256][128] (next layer)
    const float* __restrict__ nb1, const float* __restrict__ nb2,
    const float* __restrict__ bcv,  // [256] (next layer)
    bf16* __restrict__ P)
{
  __shared__ bf16 SA[64][132];   // A1 k-quarter stage; later SH (hnew bf16)
  __shared__ bf16 SW[128][72];   // weight k-quarter stage
  __shared__ bf16 SU[64][132];   // u1 [row][128]
  int tid = threadIdx.x, lane = tid & 63, w = tid >> 6;
  int rsel = lane & 15, hi = lane >> 4;
  int m0 = blockIdx.x * 64;
  int urow = w*16 + rsel;
  int grow = m0 + urow;

  f32x4 acc[8];
  #pragma unroll
  for (int nt=0;nt<8;++nt)
    #pragma unroll
    for (int r=0;r<4;++r) acc[nt][r]=0.f;

  // ---- GEMM1: u1' = nw1T @ [h|aggr]^T ----
  for (int kq=0; kq<4; ++kq){
    const float* src = (kq < 2) ? (h + (size_t)m0*128 + kq*64)
                                : (aggr + (size_t)m0*128 + (kq-2)*64);
    #pragma unroll
    for (int it=0; it<2; ++it){
      int g = tid + it*256;
      int row = g >> 3, cg = (g & 7)*8;
      const float* sp = src + (size_t)row*128 + cg;
      f32x4 u0 = *(const f32x4*)sp, u1v = *(const f32x4*)(sp+4);
      bf16x8 vv;
      vv[0]=(bf16)u0[0]; vv[1]=(bf16)u0[1]; vv[2]=(bf16)u0[2]; vv[3]=(bf16)u0[3];
      vv[4]=(bf16)u1v[0]; vv[5]=(bf16)u1v[1]; vv[6]=(bf16)u1v[2]; vv[7]=(bf16)u1v[3];
      *(bf16x8*)&SA[row][cg] = vv;
    }
    #pragma unroll
    for (int it=0; it<4; ++it){
      int g = tid + it*256;
      int row = g >> 3, cg = (g & 7)*8;
      *(bf16x8*)&SW[row][cg] = *(const bf16x8*)(nw1t + (size_t)row*256 + kq*64 + cg);
    }
    __syncthreads();
    #pragma unroll
    for (int ks=0; ks<2; ++ks){
      int kb = ks*32 + hi*8;
      bf16x8 fa = *(const bf16x8*)&SA[w*16 + rsel][kb];
      #pragma unroll
      for (int nt=0;nt<8;++nt){
        bf16x8 fw = *(const bf16x8*)&SW[nt*16 + rsel][kb];
        acc[nt] = mfma16(fw, fa, acc[nt]);
      }
    }
    __syncthreads();
  }

  // ---- u1 = silu(acc + b1) -> SU ----
  #pragma unroll
  for (int nt=0;nt<8;++nt){
    int nb = nt*16 + 4*hi;
    f32x4 b4 = *(const f32x4*)(nb1 + nb);
    uint2 pk;
    pk.x = (unsigned)bfb(silu_f(acc[nt][0] + b4[0])) | ((unsigned)bfb(silu_f(acc[nt][1] + b4[1])) << 16);
    pk.y = (unsigned)bfb(silu_f(acc[nt][2] + b4[2])) | ((unsigned)bfb(silu_f(acc[nt][3] + b4[3])) << 16);
    *(uint2*)&SU[urow][nb] = pk;
  }
  __syncthreads();

  // ---- GEMM2: hdelta' = nw2T @ u1^T ----
  #pragma unroll
  for (int nt=0;nt<8;++nt)
    #pragma unroll
    for (int r=0;r<4;++r) acc[nt][r]=0.f;
  for (int kq=0; kq<2; ++kq){
    #pragma unroll
    for (int it=0; it<4; ++it){
      int g = tid + it*256;
      int row = g >> 3, cg = (g & 7)*8;
      *(bf16x8*)&SW[row][cg] = *(const bf16x8*)(nw2t + (size_t)row*128 + kq*64 + cg);
    }
    __syncthreads();
    #pragma unroll
    for (int ks=0; ks<2; ++ks){
      int kb = ks*32 + hi*8;
      bf16x8 fa = *(const bf16x8*)&SU[w*16 + rsel][kq*64 + kb];
      #pragma unroll
      for (int nt=0;nt<8;++nt){
        bf16x8 fw = *(const bf16x8*)&SW[nt*16 + rsel][kb];
        acc[nt] = mfma16(fw, fa, acc[nt]);
      }
    }
    __syncthreads();
  }

  // ---- hnew = h + acc + b2 ; write h (f32) + SH bf16 ----
  #pragma unroll
  for (int nt=0;nt<8;++nt){
    int nb = nt*16 + 4*hi;
    f32x4 b4 = *(const f32x4*)(nb2 + nb);
    f32x4 h4 = *(const f32x4*)(h + (size_t)grow*128 + nb);
    f32x4 v;
    #pragma unroll
    for (int r=0;r<4;++r) v[r] = h4[r] + acc[nt][r] + b4[r];
    *(f32x4*)(h + (size_t)grow*128 + nb) = v;
    uint2 pk;
    pk.x = (unsigned)bfb(v[0]) | ((unsigned)bfb(v[1]) << 16);
    pk.y = (unsigned)bfb(v[2]) | ((unsigned)bfb(v[3]) << 16);
    *(uint2*)&SA[urow][nb] = pk;
  }
  __syncthreads();

  if (DOP){
    for (int nh=0; nh<2; ++nh){
      #pragma unroll
      for (int nt=0;nt<8;++nt)
        #pragma unroll
        for (int r=0;r<4;++r) acc[nt][r]=0.f;
      for (int kq=0; kq<2; ++kq){
        #pragma unroll
        for (int it=0; it<4; ++it){
          int g = tid + it*256;
          int row = g >> 3, cg = (g & 7)*8;
          *(bf16x8*)&SW[row][cg] = *(const bf16x8*)(wct + (size_t)(nh*128+row)*128 + kq*64 + cg);
        }
        __syncthreads();
        #pragma unroll
        for (int ks=0; ks<2; ++ks){
          int kb = ks*32 + hi*8;
          bf16x8 fa = *(const bf16x8*)&SA[w*16 + rsel][kq*64 + kb];
          #pragma unroll
          for (int nt=0;nt<8;++nt){
            bf16x8 fw = *(const bf16x8*)&SW[nt*16 + rsel][kb];
            acc[nt] = mfma16(fw, fa, acc[nt]);
          }
        }
        __syncthreads();
      }
      #pragma unroll
      for (int nt=0;nt<8;++nt){
        int nb = nh*128 + nt*16 + 4*hi;
        f32x4 b4 = *(const f32x4*)(bcv + nb);
        uint2 pk;
        pk.x = (unsigned)bfb(acc[nt][0] + b4[0]) | ((unsigned)bfb(acc[nt][1] + b4[1]) << 16);
        pk.y = (unsigned)bfb(acc[nt][2] + b4[2]) | ((unsigned)bfb(acc[nt][3] + b4[3]) << 16);
        *(uint2*)(P + (size_t)grow*256 + nb) = pk;
      }
    }
    f32x4 z = {0.f,0.f,0.f,0.f};
    #pragma unroll
    for (int it=0; it<8; ++it){
      int idx = tid + it*256;
      *(f32x4*)(aggr + (size_t)m0*128 + (size_t)idx*4) = z;
    }
  }
}

// ---------------- fused edge MLP + MFMA-based segmented aggregation ----------------
__global__ __launch_bounds__(512, 6) void k_edge(
    const bf16* __restrict__ P, const bf16* __restrict__ w2t,
    const float* __restrict__ w1r, const float* __restrict__ b2,
    const int4* __restrict__ rec, float* __restrict__ aggr)
{
  __shared__ char smem[32768];      // m1 [128 e][256B] swz -> m2t [128 col][256B] swz
  __shared__ int s_dst[128];
  __shared__ int s_segid[128];
  __shared__ int s_segdst[128];
  __shared__ bf16 s_sel[16][136];   // selector tile [seg][edge]
  __shared__ int s_misc[4];
  int tid = threadIdx.x, lane = tid & 63, w = tid >> 6;
  int rsel = lane & 15, hi = lane >> 4;
  int bid = blockIdx.x;
  int swb = (bid & 7) * (EE/128/8) + (bid >> 3);   // XCD-chunked, 5000%8==0
  int e0 = swb * 128;
  int col = w*16 + rsel;

  bf16x8 fb[4];
  #pragma unroll
  for (int ks=0;ks<4;++ks)
    fb[ks] = *(const bf16x8*)(w2t + (size_t)col*128 + ks*32 + hi*8);

  if (tid == 0){
    s_misc[0] = (e0 == 0) ? -2147483647 : rec[e0-1].y;
    s_misc[1] = (e0 + 128 >= EE) ? -2147483647 : rec[e0+128].y;
  }

  int cq = (tid & 15)*8;
  int er = tid >> 4;
  int4 rc[4];
  #pragma unroll
  for (int it=0; it<4; ++it) rc[it] = rec[e0 + er + it*32];
  uint4 pau[4], pbu[4];
  #pragma unroll
  for (int it=0; it<4; ++it){
    pau[it] = *(const uint4*)(P + ((size_t)rc[it].y << 8) + cq);
    pbu[it] = *(const uint4*)(P + ((size_t)rc[it].x << 8) + 128 + cq);
  }
  if (cq == 0){
    #pragma unroll
    for (int it=0; it<4; ++it) s_dst[er + it*32] = rc[it].y;
  }
  f32x4 wr0 = *(const f32x4*)(w1r + cq);
  f32x4 wr1 = *(const f32x4*)(w1r + cq + 4);
  #pragma unroll
  for (int it=0; it<4; ++it){
    float dist = __int_as_float(rc[it].z);
    bf16x8 mm;
    #pragma unroll
    for (int j=0;j<4;++j){
      unsigned ua = ((const unsigned*)&pau[it])[j];
      unsigned ub = ((const unsigned*)&pbu[it])[j];
      float al = __uint_as_float(ua << 16);
      float ah = __uint_as_float(ua & 0xFFFF0000u);
      float bl = __uint_as_float(ub << 16);
      float bh = __uint_as_float(ub & 0xFFFF0000u);
      float wlo = (j<2) ? wr0[2*j]   : wr1[2*(j-2)];
      float whi = (j<2) ? wr0[2*j+1] : wr1[2*(j-2)+1];
      mm[2*j]   = (bf16)silu_f(al + bl + dist*wlo);
      mm[2*j+1] = (bf16)silu_f(ah + bh + dist*whi);
    }
    *(bf16x8*)(smem + swz(er + it*32, cq*2)) = mm;
  }
  __syncthreads();

  // segid scan (wave 0), concurrent with GEMM1 on other waves
  if (w == 0){
    int d0 = s_dst[2*lane], d1 = s_dst[2*lane+1];
    int dm1 = (lane == 0) ? 0 : s_dst[2*lane-1];
    int h0 = (lane == 0) ? 1 : (d0 != dm1);
    int h1 = (d1 != d0);
    int p = h0 + h1, x = p;
    #pragma unroll
    for (int off=1; off<64; off<<=1){ int t = __shfl_up(x, off); if (lane>=off) x += t; }
    int excl = x - p;
    int id0 = excl + h0 - 1;
    int id1 = excl + p - 1;
    s_segid[2*lane]   = id0;
    s_segid[2*lane+1] = id1;
    if (h0) s_segdst[id0] = d0;
    if (h1) s_segdst[id1] = d1;
    if (lane == 63) s_misc[2] = id1 + 1;
  }

  // GEMM1: C[e][col] = m1 @ w2^T
  f32x4 acc[8];
  #pragma unroll
  for (int mt=0;mt<8;++mt)
    #pragma unroll
    for (int r=0;r<4;++r) acc[mt][r]=0.f;
  #pragma unroll
  for (int mt=0;mt<8;++mt){
    #pragma unroll
    for (int ks=0;ks<4;++ks){
      bf16x8 fa = *(const bf16x8*)(smem + swz(mt*16 + rsel, ks*64 + hi*16));
      acc[mt] = mfma16(fa, fb[ks], acc[mt]);
    }
  }
  __syncthreads();

  // m2^T = silu(acc + b2) -> bf16 [col][e] swizzled
  float bb = b2[col];
  #pragma unroll
  for (int mt=0;mt<8;++mt){
    uint2 pk;
    pk.x = (unsigned)bfb(silu_f(acc[mt][0] + bb)) | ((unsigned)bfb(silu_f(acc[mt][1] + bb)) << 16);
    pk.y = (unsigned)bfb(silu_f(acc[mt][2] + bb)) | ((unsigned)bfb(silu_f(acc[mt][3] + bb)) << 16);
    *(uint2*)(smem + col*256 + ((mt*32 + hi*8) ^ ((col & 7) << 4))) = pk;
  }
  __syncthreads();

  bf16x8 gb[4];
  #pragma unroll
  for (int ks=0;ks<4;++ks)
    gb[ks] = *(const bf16x8*)(smem + col*256 + ((ks*64 + hi*16) ^ ((col & 7) << 4)));
  int nseg = s_misc[2];
  bool openL = (s_dst[0]   == s_misc[0]);
  bool openR = (s_dst[127] == s_misc[1]);
  const bf16 ONE = (bf16)1.0f, ZERO = (bf16)0.0f;
  for (int st = 0; st < nseg; st += 16){
    // build selector tile in LDS (shared work, replaces per-thread bfe/cmp chains)
    __syncthreads();
    #pragma unroll
    for (int k4=0;k4<4;++k4){
      int idx = tid + k4*512;
      int s = idx >> 7, e = idx & 127;
      s_sel[s][e] = (s_segid[e] == st + s) ? ONE : ZERO;
    }
    __syncthreads();
    f32x4 racc = {0.f,0.f,0.f,0.f};
    #pragma unroll
    for (int ks=0;ks<4;++ks){
      bf16x8 sa = *(const bf16x8*)&s_sel[rsel][ks*32 + hi*8];
      racc = mfma16(sa, gb[ks], racc);
    }
    #pragma unroll
    for (int r=0;r<4;++r){
      int s = st + 4*hi + r;
      if (s < nseg){
        float v = racc[r];
        size_t off = (size_t)s_segdst[s]*128 + col;
        bool atom = (s == 0 && openL) || (s == nseg-1 && openR);
        if (atom) atomicAdd(&aggr[off], v);
        else      aggr[off] = v;
      }
    }
  }
}

// ---------------- pooling + transformer (fp32) ----------------
__device__ __forceinline__ int lbound(const int* a, int n, int key){
  int lo=0, hi=n;
  while (lo<hi){ int mid=(lo+hi)>>1; if (a[mid]<key) lo=mid+1; else hi=mid; }
  return lo;
}

__global__ __launch_bounds__(384) void k_pool_qkv(
    const float* __restrict__ h, const int* __restrict__ batch,
    const float* __restrict__ wq, const float* __restrict__ bq,
    float* __restrict__ gbuf, float* __restrict__ qkvb)
{
  __shared__ float sg[128];
  int gr = blockIdx.x, tid = threadIdx.x;
  if (tid < 128){
    int lo = lbound(batch, NN, gr), hi2 = lbound(batch, NN, gr+1);
    float s = 0.f;
    for (int n=lo;n<hi2;++n) s += h[(size_t)n*HH + tid];
    int c = hi2 - lo; if (c < 1) c = 1;
    s /= (float)c;
    sg[tid] = s; gbuf[gr*128 + tid] = s;
  }
  __syncthreads();
  float a = bq[tid];
  for (int k=0;k<128;++k) a += sg[k]*wq[k*384 + tid];
  qkvb[gr*384 + tid] = a;
}

template<int MODE>
__global__ __launch_bounds__(128) void k_tail(
    const float* __restrict__ qkv, const float* __restrict__ wo,
    const float* __restrict__ bo, const float* __restrict__ l1g,
    const float* __restrict__ l1b, const float* __restrict__ w1,
    const float* __restrict__ b1f, const float* __restrict__ w2,
    const float* __restrict__ b2f, const float* __restrict__ l2g,
    const float* __restrict__ l2b, float* __restrict__ gbuf,
    const float* __restrict__ wq2, const float* __restrict__ bq2,
    float* __restrict__ qkvb2,
    const float* __restrict__ cw1, const float* __restrict__ cb1,
    const float* __restrict__ cw2, const float* __restrict__ cb2,
    float* __restrict__ out)
{
  __shared__ float sq[128];
  __shared__ float ss[4][256];
  __shared__ float so[128];
  __shared__ float st[256];
  __shared__ float red[4];
  int r = blockIdx.x, tid = threadIdx.x;
  sq[tid] = qkv[r*384 + tid];
  __syncthreads();
  const float scale = 0.17677669529663687f;
  for (int i=tid; i<1024; i+=128){
    int hh = i >> 8, j = i & 255;
    const float* kr = qkv + j*384 + 128 + hh*32;
    const float* qr = sq + hh*32;
    float s=0;
    #pragma unroll
    for (int d=0;d<32;++d) s += qr[d]*kr[d];
    ss[hh][j] = s*scale;
  }
  __syncthreads();
  int hh = tid >> 5, sl = tid & 31;
  float m = -1e30f;
  #pragma unroll
  for (int q8=0;q8<8;++q8) m = fmaxf(m, ss[hh][sl + q8*32]);
  #pragma unroll
  for (int off=16; off; off>>=1) m = fmaxf(m, __shfl_xor(m, off, 32));
  float sum = 0.f;
  #pragma unroll
  for (int q8=0;q8<8;++q8){
    float e = __expf(ss[hh][sl+q8*32] - m);
    ss[hh][sl+q8*32] = e;
    sum += e;
  }
  #pragma unroll
  for (int off=16; off; off>>=1) sum += __shfl_xor(sum, off, 32);
  float inv = __builtin_amdgcn_rcpf(sum);
  __syncthreads();
  float accv = 0.f;
  for (int j=0;j<256;++j) accv += ss[hh][j]*qkv[j*384 + 256 + hh*32 + sl];
  so[tid] = accv*inv;
  __syncthreads();
  float a = bo[tid];
  for (int k=0;k<128;++k) a += so[k]*wo[k*128 + tid];
  float val = gbuf[r*128 + tid] + a;
  {
    float s = val, q = val*val;
    #pragma unroll
    for (int off=32; off; off>>=1){ s += __shfl_xor(s, off); q += __shfl_xor(q, off); }
    int lane = tid & 63, wv = tid >> 6;
    if (lane==0){ red[wv*2]=s; red[wv*2+1]=q; }
    __syncthreads();
    float S = red[0]+red[2], Q = red[1]+red[3];
    float mean = S*(1.0f/128.0f);
    float var = Q*(1.0f/128.0f) - mean*mean;
    float ninv = rsqrtf(var + 1e-5f);
    val = (val-mean)*ninv*l1g[tid] + l1b[tid];
  }
  sq[tid] = val;
  __syncthreads();
  float a0 = b1f[tid], a1 = b1f[tid+128];
  for (int k=0;k<128;++k){
    float gv = sq[k];
    a0 += gv*w1[k*256 + tid];
    a1 += gv*w1[k*256 + tid + 128];
  }
  st[tid]     = fmaxf(a0, 0.f);
  st[tid+128] = fmaxf(a1, 0.f);
  __syncthreads();
  float b = b2f[tid];
  for (int k=0;k<256;++k) b += st[k]*w2[k*128 + tid];
  float val2 = val + b;
  {
    float s = val2, q = val2*val2;
    #pragma unroll
    for (int off=32; off; off>>=1){ s += __shfl_xor(s, off); q += __shfl_xor(q, off); }
    int lane = tid & 63, wv = tid >> 6;
    __syncthreads();
    if (lane==0){ red[wv*2]=s; red[wv*2+1]=q; }
    __syncthreads();
    float S = red[0]+red[2], Q = red[1]+red[3];
    float mean = S*(1.0f/128.0f);
    float var = Q*(1.0f/128.0f) - mean*mean;
    float ninv = rsqrtf(var + 1e-5f);
    val2 = (val2-mean)*ninv*l2g[tid] + l2b[tid];
  }
  gbuf[r*128 + tid] = val2;
  if (MODE == 0){
    sq[tid] = val2;
    __syncthreads();
    float q0 = bq2[tid], q1 = bq2[tid+128], q2 = bq2[tid+256];
    for (int k=0;k<128;++k){
      float gv = sq[k];
      const float* wr = wq2 + k*384;
      q0 += gv*wr[tid]; q1 += gv*wr[tid+128]; q2 += gv*wr[tid+256];
    }
    qkvb2[r*384+tid]=q0; qkvb2[r*384+tid+128]=q1; qkvb2[r*384+tid+256]=q2;
  }
  if (MODE == 1){
    so[tid] = val2;
    __syncthreads();
    if (tid < 64){
      float c = cb1[tid];
      for (int k=0;k<128;++k) c += so[k]*cw1[k*64 + tid];
      c = fmaxf(c, 0.f);
      float p = c * cw2[tid];
      #pragma unroll
      for (int off=32; off; off>>=1) p += __shfl_xor(p, off);
      if (tid==0) out[r] = p + cb2[0];
    }
  }
}

// ---------------- launch ----------------
extern "C" void kernel_launch(void* const* d_in, const int* in_sizes, int n_in,
                              void* d_out, int out_size, void* d_ws, size_t ws_size,
                              hipStream_t stream)
{
  (void)in_sizes; (void)n_in; (void)out_size; (void)ws_size;
  const float* x      = (const float*)d_in[0];
  const float* pos    = (const float*)d_in[1];
  const float* emb_w  = (const float*)d_in[2];
  const float* emb_b  = (const float*)d_in[3];
  const float* edge_w1= (const float*)d_in[4];
  const float* edge_b1= (const float*)d_in[5];
  const float* edge_w2= (const float*)d_in[6];
  const float* edge_b2= (const float*)d_in[7];
  const float* node_w1= (const float*)d_in[8];
  const float* node_b1= (const float*)d_in[9];
  const float* node_w2= (const float*)d_in[10];
  const float* node_b2= (const float*)d_in[11];
  const float* qkv_w  = (const float*)d_in[12];
  const float* qkv_b  = (const float*)d_in[13];
  const float* out_w  = (const float*)d_in[14];
  const float* out_b  = (const float*)d_in[15];
  const float* ln1_g  = (const float*)d_in[16];
  const float* ln1_b  = (const float*)d_in[17];
  const float* ln2_g  = (const float*)d_in[18];
  const float* ln2_b  = (const float*)d_in[19];
  const float* ff_w1  = (const float*)d_in[20];
  const float* ff_b1  = (const float*)d_in[21];
  const float* ff_w2  = (const float*)d_in[22];
  const float* ff_b2  = (const float*)d_in[23];
  const float* cls_w1 = (const float*)d_in[24];
  const float* cls_b1 = (const float*)d_in[25];
  const float* cls_w2 = (const float*)d_in[26];
  const float* cls_b2 = (const float*)d_in[27];
  const int* ei       = (const int*)d_in[28];
  const int* batch    = (const int*)d_in[29];
  float* out = (float*)d_out;

  uint8_t* wp = (uint8_t*)d_ws;
  auto take = [&](size_t nb)->void*{ void* r = wp; wp += (nb + 255) & ~(size_t)255; return r; };
  float* h      = (float*)take((size_t)NN*HH*4);
  bf16*  P      = (bf16*) take((size_t)NN*256*2);
  float* aggr   = (float*)take((size_t)NN*HH*4);
  int*   cnt    = (int*)  take((size_t)NN*4);
  int*   cursor = (int*)  take((size_t)NN*4);
  int*   parts  = (int*)  take((size_t)64*4);
  int4*  rec    = (int4*) take((size_t)EE*16);
  bf16*  wcatT  = (bf16*) take((size_t)3*256*128*2);
  bf16*  w2T    = (bf16*) take((size_t)3*128*128*2);
  bf16*  nw1T   = (bf16*) take((size_t)3*128*256*2);
  bf16*  nw2T   = (bf16*) take((size_t)3*128*128*2);
  float* bcat   = (float*)take((size_t)3*256*4);
  float* gbuf   = (float*)take((size_t)GG*HH*4);
  float* qkvb   = (float*)take((size_t)GG*384*4);
  float* qkvb2  = (float*)take((size_t)GG*384*4);

  dim3 b256(256);
  k_prep<<<dim3(21312), b256, 0, stream>>>(edge_w1, edge_w2, node_w1, node_w2,
    edge_b1, x, emb_w, emb_b, wcatT, w2T, nw1T, nw2T, bcat, h, cnt);
  k_hist<<<dim3(EE/256), b256, 0, stream>>>(ei + EE, cnt);
  k_scanA<<<dim3(10), dim3(1024), 0, stream>>>(cnt, cursor, parts, NN);
  k_scanB<<<dim3(1), dim3(64), 0, stream>>>(parts, 10);
  k_scatter<<<dim3(EE/256), b256, 0, stream>>>(ei, pos, cursor, parts, rec);

  k_pgen<<<dim3(625), b256, 0, stream>>>(h, wcatT, bcat, P, aggr);

  for (int l=0;l<3;++l){
    k_edge<<<dim3(EE/128), dim3(512), 0, stream>>>(P, w2T + (size_t)l*16384,
      edge_w1 + ((size_t)l*257 + 256)*128, edge_b2 + (size_t)l*128, rec, aggr);
    if (l < 2){
      k_node<true><<<dim3(625), b256, 0, stream>>>(h, aggr,
        nw1T + (size_t)l*32768, nw2T + (size_t)l*16384, wcatT + (size_t)(l+1)*32768,
        node_b1 + (size_t)l*128, node_b2 + (size_t)l*128, bcat + (size_t)(l+1)*256, P);
    } else {
      k_node<false><<<dim3(625), b256, 0, stream>>>(h, aggr,
        nw1T + (size_t)l*32768, nw2T + (size_t)l*16384, wcatT,
        node_b1 + (size_t)l*128, node_b2 + (size_t)l*128, bcat, P);
    }
  }

  k_pool_qkv<<<dim3(GG), dim3(384), 0, stream>>>(h, batch, qkv_w, qkv_b, gbuf, qkvb);
  k_tail<0><<<dim3(GG), dim3(128), 0, stream>>>(qkvb, out_w, out_b,
    ln1_g, ln1_b, ff_w1, ff_b1, ff_w2, ff_b2, ln2_g, ln2_b, gbuf,
    qkv_w + (size_t)128*384, qkv_b + 384, qkvb2,
    nullptr, nullptr, nullptr, nullptr, nullptr);
  k_tail<1><<<dim3(GG), dim3(128), 0, stream>>>(qkvb2, out_w + (size_t)128*128, out_b + 128,
    ln1_g + 128, ln1_b + 128, ff_w1 + (size_t)128*256, ff_b1 + 256,
    ff_w2 + (size_t)256*128, ff_b2 + 128, ln2_g + 128, ln2_b + 128, gbuf,
    nullptr, nullptr, nullptr,
    cls_w1, cls_b1, cls_w2, cls_b2, out);
}

// Round 8
// 629.138 us; speedup vs baseline: 1.6729x; 1.0035x over previous
//
#include <hip/hip_runtime.h>
#include <hip/hip_bf16.h>
#include <stdint.h>

#define NN 40000
#define EE 640000
#define GG 256
#define FFE 9
#define HH 128

typedef __bf16 bf16;
typedef __bf16 bf16x8 __attribute__((ext_vector_type(8)));
typedef float f32x4 __attribute__((ext_vector_type(4)));

__device__ __forceinline__ f32x4 mfma16(bf16x8 a, bf16x8 b, f32x4 c){
  return __builtin_amdgcn_mfma_f32_16x16x32_bf16(a, b, c, 0, 0, 0);
}
__device__ __forceinline__ float silu_f(float x){
  return x * __builtin_amdgcn_rcpf(1.0f + __expf(-x));
}
__device__ __forceinline__ uint16_t bfb(float x){ bf16 h=(bf16)x; return *(uint16_t*)&h; }
// byte-offset XOR swizzle for [row][256B] LDS tiles
__device__ __forceinline__ int swz(int row, int cb){
  return row*256 + (cb ^ ((row & 7) << 4));
}

// ---------------- merged prep ----------------
__global__ __launch_bounds__(256) void k_prep(
    const float* __restrict__ edge_w1, const float* __restrict__ edge_w2,
    const float* __restrict__ node_w1, const float* __restrict__ node_w2,
    const float* __restrict__ edge_b1,
    const float* __restrict__ x, const float* __restrict__ emb_w,
    const float* __restrict__ emb_b,
    bf16* __restrict__ wcatT, bf16* __restrict__ w2T,
    bf16* __restrict__ nw1T, bf16* __restrict__ nw2T,
    float* __restrict__ bcat, float* __restrict__ h,
    int* __restrict__ cnt)
{
  __shared__ float sx[64][9];
  __shared__ float swt[9][128];
  __shared__ float sbv[128];
  int b = blockIdx.x, tid = threadIdx.x;
  if (b < 192){
    int l = b/64; int t2 = (b%64)*256 + tid;
    int n = t2 >> 7, k = t2 & 127;
    wcatT[(size_t)l*32768 + n*128 + k] = (bf16)edge_w1[(size_t)l*32896 + k*128 + n];
  } else if (b < 384){
    int lb = b - 192; int l = lb/64; int t2 = (lb%64)*256 + tid;
    int n = t2 >> 7, k = t2 & 127;
    wcatT[(size_t)l*32768 + 16384 + n*128 + k] = (bf16)edge_w1[(size_t)l*32896 + (128+k)*128 + n];
  } else if (b < 576){
    int lb = b - 384; int l = lb/64; int t2 = (lb%64)*256 + tid;
    int n = t2 >> 7, k = t2 & 127;
    w2T[(size_t)l*16384 + n*128 + k] = (bf16)edge_w2[(size_t)l*16384 + k*128 + n];
  } else if (b < 960){
    int lb = b - 576; int l = lb/128; int t2 = (lb%128)*256 + tid;
    int n = t2 >> 8, k = t2 & 255;
    nw1T[(size_t)l*32768 + n*256 + k] = (bf16)node_w1[(size_t)l*32768 + k*128 + n];
  } else if (b < 1152){
    int lb = b - 960; int l = lb/64; int t2 = (lb%64)*256 + tid;
    int n = t2 >> 7, k = t2 & 127;
    nw2T[(size_t)l*16384 + n*128 + k] = (bf16)node_w2[(size_t)l*16384 + k*128 + n];
  } else if (b < 1155){
    int l = b - 1152;
    bcat[l*256 + tid] = (tid < 128) ? edge_b1[l*128 + tid] : 0.0f;
  } else if (b < 1312){
    int i = (b - 1155)*256 + tid;
    if (i < NN) cnt[i] = 0;
  } else {
    // embedding: 625 blocks x 64 nodes, x/emb_w staged in LDS
    int m0 = (b - 1312) * 64;
    if (tid < 128) sbv[tid] = emb_b[tid];
    for (int i = tid; i < 1152; i += 256) swt[i>>7][i&127] = emb_w[i];
    for (int i = tid; i < 576; i += 256) sx[i/9][i%9] = x[(size_t)m0*9 + i];
    __syncthreads();
    int row = tid >> 2, c0 = (tid & 3) * 32;
    float xr[9];
    #pragma unroll
    for (int k=0;k<9;++k) xr[k] = sx[row][k];
    for (int j=0;j<32;j+=4){
      f32x4 a;
      #pragma unroll
      for (int r=0;r<4;++r) a[r] = sbv[c0+j+r];
      #pragma unroll
      for (int k=0;k<9;++k){
        #pragma unroll
        for (int r=0;r<4;++r) a[r] += xr[k]*swt[k][c0+j+r];
      }
      *(f32x4*)(h + (size_t)(m0+row)*128 + c0 + j) = a;
    }
  }
}

// ---------------- counting sort by dst ----------------
__global__ __launch_bounds__(256) void k_hist(const int* __restrict__ dst, int* __restrict__ cnt){
  int e = blockIdx.x*256 + threadIdx.x;
  if (e < EE) atomicAdd(&cnt[dst[e]], 1);
}

// parallel scan: per-4096-chunk local exclusive prefix + chunk totals
__global__ __launch_bounds__(1024) void k_scanA(const int* __restrict__ cnt,
    int* __restrict__ cursor, int* __restrict__ partials, int n)
{
  __shared__ int s_wsum[16];
  int tid = threadIdx.x, lane = tid & 63, wv = tid >> 6;
  int i = blockIdx.x*4096 + tid*4;
  int c0 = (i  <n)? cnt[i  ] : 0;
  int c1 = (i+1<n)? cnt[i+1] : 0;
  int c2 = (i+2<n)? cnt[i+2] : 0;
  int c3 = (i+3<n)? cnt[i+3] : 0;
  int t0 = c0, t1 = t0+c1, t2 = t1+c2, t3 = t2+c3;
  int xx = t3;
  #pragma unroll
  for (int off=1; off<64; off<<=1){ int t = __shfl_up(xx, off); if (lane>=off) xx += t; }
  if (lane==63) s_wsum[wv] = xx;
  __syncthreads();
  if (wv==0 && lane<16){
    int y = s_wsum[lane];
    #pragma unroll
    for (int off=1; off<16; off<<=1){ int t = __shfl_up(y, off, 16); if (lane>=off) y += t; }
    s_wsum[lane] = y;
  }
  __syncthreads();
  int woff = wv ? s_wsum[wv-1] : 0;
  int eb = woff + xx - t3;
  if (i  <n) cursor[i  ] = eb;
  if (i+1<n) cursor[i+1] = eb + t0;
  if (i+2<n) cursor[i+2] = eb + t1;
  if (i+3<n) cursor[i+3] = eb + t2;
  if (tid==1023) partials[blockIdx.x] = woff + xx;
}

__global__ __launch_bounds__(256) void k_scatter(
    const int* __restrict__ ei, const float* __restrict__ pos,
    int* __restrict__ cursor, const int* __restrict__ parts, int4* __restrict__ rec)
{
  __shared__ int offs_s[16];
  int tid = threadIdx.x;
  if (tid < 16){
    int v = (tid < 10) ? parts[tid] : 0;
    int xp = v;
    #pragma unroll
    for (int off=1; off<16; off<<=1){ int t = __shfl_up(xp, off, 16); if (tid>=off) xp += t; }
    offs_s[tid] = xp - v;   // exclusive prefix
  }
  __syncthreads();
  int e = blockIdx.x*256 + tid;
  if (e >= EE) return;
  int s = ei[e], d = ei[EE + e];
  int p = atomicAdd(&cursor[d], 1) + offs_s[d >> 12];
  float dx = pos[d*3+0]-pos[s*3+0];
  float dy = pos[d*3+1]-pos[s*3+1];
  float dz = pos[d*3+2]-pos[s*3+2];
  int4 rc; rc.x = s; rc.y = d; rc.z = __float_as_int(sqrtf(dx*dx+dy*dy+dz*dz)); rc.w = 0;
  rec[p] = rc;
}

// ---------------- initial P: P = h @ [W1d|W1s] + bcat, fused aggr zero ----------------
__global__ __launch_bounds__(256) void k_pgen(
    const float* __restrict__ h, const bf16* __restrict__ wct,
    const float* __restrict__ bcv, bf16* __restrict__ P, float* __restrict__ aggr)
{
  __shared__ bf16 SA[64][136];
  __shared__ bf16 SW[128][136];
  int tid = threadIdx.x, lane = tid & 63, w = tid >> 6;
  int rsel = lane & 15, hi = lane >> 4;
  int m0 = blockIdx.x * 64;
  f32x4 z = {0.f,0.f,0.f,0.f};
  #pragma unroll
  for (int it=0; it<8; ++it)
    *(f32x4*)(aggr + (size_t)m0*128 + (size_t)(tid + it*256)*4) = z;
  #pragma unroll
  for (int it=0; it<4; ++it){
    int idx = tid + it*256;
    int row = idx >> 4, cg = (idx & 15)*8;
    const float* sp = h + (size_t)(m0+row)*128 + cg;
    f32x4 u0 = *(const f32x4*)sp, u1v = *(const f32x4*)(sp+4);
    bf16x8 vv;
    vv[0]=(bf16)u0[0]; vv[1]=(bf16)u0[1]; vv[2]=(bf16)u0[2]; vv[3]=(bf16)u0[3];
    vv[4]=(bf16)u1v[0]; vv[5]=(bf16)u1v[1]; vv[6]=(bf16)u1v[2]; vv[7]=(bf16)u1v[3];
    *(bf16x8*)&SA[row][cg] = vv;
  }
  __syncthreads();
  int urow = w*16 + rsel;
  for (int nh=0; nh<2; ++nh){
    #pragma unroll
    for (int it=0; it<8; ++it){
      int idx = tid + it*256;
      int row = idx >> 4, cg = (idx & 15)*8;
      *(bf16x8*)&SW[row][cg] = *(const bf16x8*)(wct + (size_t)(nh*128+row)*128 + cg);
    }
    __syncthreads();
    f32x4 acc[8];
    #pragma unroll
    for (int nt=0;nt<8;++nt)
      #pragma unroll
      for (int r=0;r<4;++r) acc[nt][r]=0.f;
    #pragma unroll
    for (int ks=0; ks<4; ++ks){
      int kb = ks*32 + hi*8;
      bf16x8 fa = *(const bf16x8*)&SA[urow][kb];
      #pragma unroll
      for (int nt=0;nt<8;++nt){
        bf16x8 fw = *(const bf16x8*)&SW[nt*16 + rsel][kb];
        acc[nt] = mfma16(fw, fa, acc[nt]);
      }
    }
    __syncthreads();
    #pragma unroll
    for (int nt=0;nt<8;++nt){
      int nb = nh*128 + nt*16 + 4*hi;
      f32x4 b4 = *(const f32x4*)(bcv + nb);
      uint2 pk;
      pk.x = (unsigned)bfb(acc[nt][0] + b4[0]) | ((unsigned)bfb(acc[nt][1] + b4[1]) << 16);
      pk.y = (unsigned)bfb(acc[nt][2] + b4[2]) | ((unsigned)bfb(acc[nt][3] + b4[3]) << 16);
      *(uint2*)(P + (size_t)(m0+urow)*256 + nb) = pk;
    }
  }
}

// ---------------- fused node MLP (512 threads, 8 waves) ----------------
// wave w owns n-cols [w*16, w*16+16); 4 row-tiles each; {stage; sync; mfma; sync} per k-quarter.
template<bool DOP>
__global__ __launch_bounds__(512) void k_node(
    float* h, float* aggr,
    const bf16* __restrict__ nw1t,  // [128][256]
    const bf16* __restrict__ nw2t,  // [128][128]
    const bf16* __restrict__ wct,   // [256][128] (next layer)
    const float* __restrict__ nb1, const float* __restrict__ nb2,
    const float* __restrict__ bcv,  // [256] (next layer)
    bf16* __restrict__ P)
{
  __shared__ bf16 SA[64][68];    // A k-quarter stage [row][64k]
  __shared__ bf16 SW[128][72];   // weight k-quarter stage [n][64k]
  __shared__ bf16 SU[64][132];   // u1 [row][128]
  __shared__ bf16 SH[64][132];   // hnew bf16 [row][128]
  int tid = threadIdx.x, lane = tid & 63, w = tid >> 6;
  int rsel = lane & 15, hi = lane >> 4;
  int m0 = blockIdx.x * 64;
  int nbase = w*16 + 4*hi;

  f32x4 acc[4];
  #pragma unroll
  for (int rt=0;rt<4;++rt)
    #pragma unroll
    for (int r=0;r<4;++r) acc[rt][r]=0.f;

  // ---- GEMM1: u1' = nw1T @ [h|aggr]^T, k=256 in quarters ----
  for (int kq=0; kq<4; ++kq){
    const float* src = (kq < 2) ? (h + (size_t)m0*128 + kq*64)
                                : (aggr + (size_t)m0*128 + (kq-2)*64);
    {
      int g = tid, row = g >> 3, cg = (g & 7)*8;
      const float* sp = src + (size_t)row*128 + cg;
      f32x4 u0 = *(const f32x4*)sp, u1v = *(const f32x4*)(sp+4);
      bf16x8 vv;
      vv[0]=(bf16)u0[0]; vv[1]=(bf16)u0[1]; vv[2]=(bf16)u0[2]; vv[3]=(bf16)u0[3];
      vv[4]=(bf16)u1v[0]; vv[5]=(bf16)u1v[1]; vv[6]=(bf16)u1v[2]; vv[7]=(bf16)u1v[3];
      *(bf16x8*)&SA[row][cg] = vv;
    }
    #pragma unroll
    for (int it=0; it<2; ++it){
      int g = tid + it*512, row = g >> 3, cg = (g & 7)*8;
      *(bf16x8*)&SW[row][cg] = *(const bf16x8*)(nw1t + (size_t)row*256 + kq*64 + cg);
    }
    __syncthreads();
    #pragma unroll
    for (int ks=0; ks<2; ++ks){
      int kb = ks*32 + hi*8;
      bf16x8 fw = *(const bf16x8*)&SW[w*16 + rsel][kb];
      #pragma unroll
      for (int rt=0; rt<4; ++rt){
        bf16x8 fa = *(const bf16x8*)&SA[rt*16 + rsel][kb];
        acc[rt] = mfma16(fw, fa, acc[rt]);
      }
    }
    __syncthreads();
  }

  // ---- u1 = silu(acc + b1) -> SU[row][n] ----
  {
    f32x4 b4 = *(const f32x4*)(nb1 + nbase);
    #pragma unroll
    for (int rt=0; rt<4; ++rt){
      uint2 pk;
      pk.x = (unsigned)bfb(silu_f(acc[rt][0]+b4[0])) | ((unsigned)bfb(silu_f(acc[rt][1]+b4[1]))<<16);
      pk.y = (unsigned)bfb(silu_f(acc[rt][2]+b4[2])) | ((unsigned)bfb(silu_f(acc[rt][3]+b4[3]))<<16);
      *(uint2*)&SU[rt*16 + rsel][nbase] = pk;
    }
  }

  // ---- GEMM2: hdelta' = nw2T @ u1^T, k=128 ----
  #pragma unroll
  for (int rt=0;rt<4;++rt)
    #pragma unroll
    for (int r=0;r<4;++r) acc[rt][r]=0.f;
  for (int kq=0; kq<2; ++kq){
    #pragma unroll
    for (int it=0; it<2; ++it){
      int g = tid + it*512, row = g >> 3, cg = (g & 7)*8;
      *(bf16x8*)&SW[row][cg] = *(const bf16x8*)(nw2t + (size_t)row*128 + kq*64 + cg);
    }
    __syncthreads();
    #pragma unroll
    for (int ks=0; ks<2; ++ks){
      int kb = ks*32 + hi*8;
      bf16x8 fw = *(const bf16x8*)&SW[w*16 + rsel][kb];
      #pragma unroll
      for (int rt=0; rt<4; ++rt){
        bf16x8 fa = *(const bf16x8*)&SU[rt*16 + rsel][kq*64 + kb];
        acc[rt] = mfma16(fw, fa, acc[rt]);
      }
    }
    __syncthreads();
  }

  // ---- hnew = h + acc + b2 ; write h (f32) + SH (bf16) ----
  {
    f32x4 c4 = *(const f32x4*)(nb2 + nbase);
    #pragma unroll
    for (int rt=0; rt<4; ++rt){
      int grow = m0 + rt*16 + rsel;
      f32x4 h4 = *(const f32x4*)(h + (size_t)grow*128 + nbase);
      f32x4 v;
      #pragma unroll
      for (int r=0;r<4;++r) v[r] = h4[r] + acc[rt][r] + c4[r];
      *(f32x4*)(h + (size_t)grow*128 + nbase) = v;
      uint2 pk;
      pk.x = (unsigned)bfb(v[0]) | ((unsigned)bfb(v[1]) << 16);
      pk.y = (unsigned)bfb(v[2]) | ((unsigned)bfb(v[3]) << 16);
      *(uint2*)&SH[rt*16 + rsel][nbase] = pk;
    }
  }

  if (DOP){
    for (int nh=0; nh<2; ++nh){
      f32x4 a3[4];
      #pragma unroll
      for (int rt=0;rt<4;++rt)
        #pragma unroll
        for (int r=0;r<4;++r) a3[rt][r]=0.f;
      for (int kq=0; kq<2; ++kq){
        #pragma unroll
        for (int it=0; it<2; ++it){
          int g = tid + it*512, row = g >> 3, cg = (g & 7)*8;
          *(bf16x8*)&SW[row][cg] = *(const bf16x8*)(wct + (size_t)(nh*128+row)*128 + kq*64 + cg);
        }
        __syncthreads();
        #pragma unroll
        for (int ks=0; ks<2; ++ks){
          int kb = ks*32 + hi*8;
          bf16x8 fw = *(const bf16x8*)&SW[w*16 + rsel][kb];
          #pragma unroll
          for (int rt=0; rt<4; ++rt){
            bf16x8 fa = *(const bf16x8*)&SH[rt*16 + rsel][kq*64 + kb];
            a3[rt] = mfma16(fw, fa, a3[rt]);
          }
        }
        __syncthreads();
      }
      f32x4 bb4 = *(const f32x4*)(bcv + nh*128 + nbase);
      #pragma unroll
      for (int rt=0; rt<4; ++rt){
        int grow = m0 + rt*16 + rsel;
        uint2 pk;
        pk.x = (unsigned)bfb(a3[rt][0]+bb4[0]) | ((unsigned)bfb(a3[rt][1]+bb4[1])<<16);
        pk.y = (unsigned)bfb(a3[rt][2]+bb4[2]) | ((unsigned)bfb(a3[rt][3]+bb4[3])<<16);
        *(uint2*)(P + (size_t)grow*256 + nh*128 + nbase) = pk;
      }
    }
    f32x4 z = {0.f,0.f,0.f,0.f};
    #pragma unroll
    for (int it=0; it<4; ++it)
      *(f32x4*)(aggr + (size_t)m0*128 + (size_t)(tid + it*512)*4) = z;
  }
}

// ---------------- fused edge MLP + MFMA-based segmented aggregation ----------------
__global__ __launch_bounds__(512, 6) void k_edge(
    const bf16* __restrict__ P, const bf16* __restrict__ w2t,
    const float* __restrict__ w1r, const float* __restrict__ b2,
    const int4* __restrict__ rec, float* __restrict__ aggr)
{
  __shared__ char smem[32768];      // m1 [128 e][256B] swz -> m2t [128 col][256B] swz
  __shared__ int s_dst[128];
  __shared__ int s_segid[128];
  __shared__ int s_segdst[128];
  __shared__ bf16 s_sel[16][136];   // selector tile [seg][edge]
  __shared__ int s_misc[4];
  int tid = threadIdx.x, lane = tid & 63, w = tid >> 6;
  int rsel = lane & 15, hi = lane >> 4;
  int bid = blockIdx.x;
  int swb = (bid & 7) * (EE/128/8) + (bid >> 3);   // XCD-chunked, 5000%8==0
  int e0 = swb * 128;
  int col = w*16 + rsel;

  bf16x8 fb[4];
  #pragma unroll
  for (int ks=0;ks<4;++ks)
    fb[ks] = *(const bf16x8*)(w2t + (size_t)col*128 + ks*32 + hi*8);

  if (tid == 0){
    s_misc[0] = (e0 == 0) ? -2147483647 : rec[e0-1].y;
    s_misc[1] = (e0 + 128 >= EE) ? -2147483647 : rec[e0+128].y;
  }

  int cq = (tid & 15)*8;
  int er = tid >> 4;
  int4 rc[4];
  #pragma unroll
  for (int it=0; it<4; ++it) rc[it] = rec[e0 + er + it*32];
  uint4 pau[4], pbu[4];
  #pragma unroll
  for (int it=0; it<4; ++it){
    pau[it] = *(const uint4*)(P + ((size_t)rc[it].y << 8) + cq);
    pbu[it] = *(const uint4*)(P + ((size_t)rc[it].x << 8) + 128 + cq);
  }
  if (cq == 0){
    #pragma unroll
    for (int it=0; it<4; ++it) s_dst[er + it*32] = rc[it].y;
  }
  f32x4 wr0 = *(const f32x4*)(w1r + cq);
  f32x4 wr1 = *(const f32x4*)(w1r + cq + 4);
  #pragma unroll
  for (int it=0; it<4; ++it){
    float dist = __int_as_float(rc[it].z);
    bf16x8 mm;
    #pragma unroll
    for (int j=0;j<4;++j){
      unsigned ua = ((const unsigned*)&pau[it])[j];
      unsigned ub = ((const unsigned*)&pbu[it])[j];
      float al = __uint_as_float(ua << 16);
      float ah = __uint_as_float(ua & 0xFFFF0000u);
      float bl = __uint_as_float(ub << 16);
      float bh = __uint_as_float(ub & 0xFFFF0000u);
      float wlo = (j<2) ? wr0[2*j]   : wr1[2*(j-2)];
      float whi = (j<2) ? wr0[2*j+1] : wr1[2*(j-2)+1];
      mm[2*j]   = (bf16)silu_f(al + bl + dist*wlo);
      mm[2*j+1] = (bf16)silu_f(ah + bh + dist*whi);
    }
    *(bf16x8*)(smem + swz(er + it*32, cq*2)) = mm;
  }
  __syncthreads();

  if (w == 0){
    int d0 = s_dst[2*lane], d1 = s_dst[2*lane+1];
    int dm1 = (lane == 0) ? 0 : s_dst[2*lane-1];
    int h0 = (lane == 0) ? 1 : (d0 != dm1);
    int h1 = (d1 != d0);
    int p = h0 + h1, x = p;
    #pragma unroll
    for (int off=1; off<64; off<<=1){ int t = __shfl_up(x, off); if (lane>=off) x += t; }
    int excl = x - p;
    int id0 = excl + h0 - 1;
    int id1 = excl + p - 1;
    s_segid[2*lane]   = id0;
    s_segid[2*lane+1] = id1;
    if (h0) s_segdst[id0] = d0;
    if (h1) s_segdst[id1] = d1;
    if (lane == 63) s_misc[2] = id1 + 1;
  }

  // GEMM1: C[e][col] = m1 @ w2^T
  f32x4 acc[8];
  #pragma unroll
  for (int mt=0;mt<8;++mt)
    #pragma unroll
    for (int r=0;r<4;++r) acc[mt][r]=0.f;
  #pragma unroll
  for (int mt=0;mt<8;++mt){
    #pragma unroll
    for (int ks=0;ks<4;++ks){
      bf16x8 fa = *(const bf16x8*)(smem + swz(mt*16 + rsel, ks*64 + hi*16));
      acc[mt] = mfma16(fa, fb[ks], acc[mt]);
    }
  }
  __syncthreads();

  // m2^T = silu(acc + b2) -> bf16 [col][e] swizzled
  float bb = b2[col];
  #pragma unroll
  for (int mt=0;mt<8;++mt){
    uint2 pk;
    pk.x = (unsigned)bfb(silu_f(acc[mt][0] + bb)) | ((unsigned)bfb(silu_f(acc[mt][1] + bb)) << 16);
    pk.y = (unsigned)bfb(silu_f(acc[mt][2] + bb)) | ((unsigned)bfb(silu_f(acc[mt][3] + bb)) << 16);
    *(uint2*)(smem + col*256 + ((mt*32 + hi*8) ^ ((col & 7) << 4))) = pk;
  }
  __syncthreads();

  bf16x8 gb[4];
  #pragma unroll
  for (int ks=0;ks<4;++ks)
    gb[ks] = *(const bf16x8*)(smem + col*256 + ((ks*64 + hi*16) ^ ((col & 7) << 4)));
  int nseg = s_misc[2];
  bool openL = (s_dst[0]   == s_misc[0]);
  bool openR = (s_dst[127] == s_misc[1]);
  const bf16 ONE = (bf16)1.0f, ZERO = (bf16)0.0f;
  for (int st = 0; st < nseg; st += 16){
    __syncthreads();
    #pragma unroll
    for (int k4=0;k4<4;++k4){
      int idx = tid + k4*512;
      int s = idx >> 7, e = idx & 127;
      s_sel[s][e] = (s_segid[e] == st + s) ? ONE : ZERO;
    }
    __syncthreads();
    f32x4 racc = {0.f,0.f,0.f,0.f};
    #pragma unroll
    for (int ks=0;ks<4;++ks){
      bf16x8 sa = *(const bf16x8*)&s_sel[rsel][ks*32 + hi*8];
      racc = mfma16(sa, gb[ks], racc);
    }
    #pragma unroll
    for (int r=0;r<4;++r){
      int s = st + 4*hi + r;
      if (s < nseg){
        float v = racc[r];
        size_t off = (size_t)s_segdst[s]*128 + col;
        bool atom = (s == 0 && openL) || (s == nseg-1 && openR);
        if (atom) atomicAdd(&aggr[off], v);
        else      aggr[off] = v;
      }
    }
  }
}

// ---------------- pooling + transformer (fp32) ----------------
__device__ __forceinline__ int lbound(const int* a, int n, int key){
  int lo=0, hi=n;
  while (lo<hi){ int mid=(lo+hi)>>1; if (a[mid]<key) lo=mid+1; else hi=mid; }
  return lo;
}

__global__ __launch_bounds__(384) void k_pool_qkv(
    const float* __restrict__ h, const int* __restrict__ batch,
    const float* __restrict__ wq, const float* __restrict__ bq,
    float* __restrict__ gbuf, float* __restrict__ qkvb)
{
  __shared__ float sg[128];
  int gr = blockIdx.x, tid = threadIdx.x;
  if (tid < 128){
    int lo = lbound(batch, NN, gr), hi2 = lbound(batch, NN, gr+1);
    float s = 0.f;
    for (int n=lo;n<hi2;++n) s += h[(size_t)n*HH + tid];
    int c = hi2 - lo; if (c < 1) c = 1;
    s /= (float)c;
    sg[tid] = s; gbuf[gr*128 + tid] = s;
  }
  __syncthreads();
  float a = bq[tid];
  for (int k=0;k<128;++k) a += sg[k]*wq[k*384 + tid];
  qkvb[gr*384 + tid] = a;
}

template<int MODE>
__global__ __launch_bounds__(128) void k_tail(
    const float* __restrict__ qkv, const float* __restrict__ wo,
    const float* __restrict__ bo, const float* __restrict__ l1g,
    const float* __restrict__ l1b, const float* __restrict__ w1,
    const float* __restrict__ b1f, const float* __restrict__ w2,
    const float* __restrict__ b2f, const float* __restrict__ l2g,
    const float* __restrict__ l2b, float* __restrict__ gbuf,
    const float* __restrict__ wq2, const float* __restrict__ bq2,
    float* __restrict__ qkvb2,
    const float* __restrict__ cw1, const float* __restrict__ cb1,
    const float* __restrict__ cw2, const float* __restrict__ cb2,
    float* __restrict__ out)
{
  __shared__ float sq[128];
  __shared__ float ss[4][256];
  __shared__ float so[128];
  __shared__ float st[256];
  __shared__ float red[4];
  int r = blockIdx.x, tid = threadIdx.x;
  sq[tid] = qkv[r*384 + tid];
  __syncthreads();
  const float scale = 0.17677669529663687f;
  for (int i=tid; i<1024; i+=128){
    int hh = i >> 8, j = i & 255;
    const float* kr = qkv + j*384 + 128 + hh*32;
    const float* qr = sq + hh*32;
    float s=0;
    #pragma unroll
    for (int d=0;d<32;++d) s += qr[d]*kr[d];
    ss[hh][j] = s*scale;
  }
  __syncthreads();
  int hh = tid >> 5, sl = tid & 31;
  float m = -1e30f;
  #pragma unroll
  for (int q8=0;q8<8;++q8) m = fmaxf(m, ss[hh][sl + q8*32]);
  #pragma unroll
  for (int off=16; off; off>>=1) m = fmaxf(m, __shfl_xor(m, off, 32));
  float sum = 0.f;
  #pragma unroll
  for (int q8=0;q8<8;++q8){
    float e = __expf(ss[hh][sl+q8*32] - m);
    ss[hh][sl+q8*32] = e;
    sum += e;
  }
  #pragma unroll
  for (int off=16; off; off>>=1) sum += __shfl_xor(sum, off, 32);
  float inv = __builtin_amdgcn_rcpf(sum);
  __syncthreads();
  float accv = 0.f;
  for (int j=0;j<256;++j) accv += ss[hh][j]*qkv[j*384 + 256 + hh*32 + sl];
  so[tid] = accv*inv;
  __syncthreads();
  float a = bo[tid];
  for (int k=0;k<128;++k) a += so[k]*wo[k*128 + tid];
  float val = gbuf[r*128 + tid] + a;
  {
    float s = val, q = val*val;
    #pragma unroll
    for (int off=32; off; off>>=1){ s += __shfl_xor(s, off); q += __shfl_xor(q, off); }
    int lane = tid & 63, wv = tid >> 6;
    if (lane==0){ red[wv*2]=s; red[wv*2+1]=q; }
    __syncthreads();
    float S = red[0]+red[2], Q = red[1]+red[3];
    float mean = S*(1.0f/128.0f);
    float var = Q*(1.0f/128.0f) - mean*mean;
    float ninv = rsqrtf(var + 1e-5f);
    val = (val-mean)*ninv*l1g[tid] + l1b[tid];
  }
  sq[tid] = val;
  __syncthreads();
  float a0 = b1f[tid], a1 = b1f[tid+128];
  for (int k=0;k<128;++k){
    float gv = sq[k];
    a0 += gv*w1[k*256 + tid];
    a1 += gv*w1[k*256 + tid + 128];
  }
  st[tid]     = fmaxf(a0, 0.f);
  st[tid+128] = fmaxf(a1, 0.f);
  __syncthreads();
  float b = b2f[tid];
  for (int k=0;k<256;++k) b += st[k]*w2[k*128 + tid];
  float val2 = val + b;
  {
    float s = val2, q = val2*val2;
    #pragma unroll
    for (int off=32; off; off>>=1){ s += __shfl_xor(s, off); q += __shfl_xor(q, off); }
    int lane = tid & 63, wv = tid >> 6;
    __syncthreads();
    if (lane==0){ red[wv*2]=s; red[wv*2+1]=q; }
    __syncthreads();
    float S = red[0]+red[2], Q = red[1]+red[3];
    float mean = S*(1.0f/128.0f);
    float var = Q*(1.0f/128.0f) - mean*mean;
    float ninv = rsqrtf(var + 1e-5f);
    val2 = (val2-mean)*ninv*l2g[tid] + l2b[tid];
  }
  gbuf[r*128 + tid] = val2;
  if (MODE == 0){
    sq[tid] = val2;
    __syncthreads();
    float q0 = bq2[tid], q1 = bq2[tid+128], q2 = bq2[tid+256];
    for (int k=0;k<128;++k){
      float gv = sq[k];
      const float* wr = wq2 + k*384;
      q0 += gv*wr[tid]; q1 += gv*wr[tid+128]; q2 += gv*wr[tid+256];
    }
    qkvb2[r*384+tid]=q0; qkvb2[r*384+tid+128]=q1; qkvb2[r*384+tid+256]=q2;
  }
  if (MODE == 1){
    so[tid] = val2;
    __syncthreads();
    if (tid < 64){
      float c = cb1[tid];
      for (int k=0;k<128;++k) c += so[k]*cw1[k*64 + tid];
      c = fmaxf(c, 0.f);
      float p = c * cw2[tid];
      #pragma unroll
      for (int off=32; off; off>>=1) p += __shfl_xor(p, off);
      if (tid==0) out[r] = p + cb2[0];
    }
  }
}

// ---------------- launch ----------------
extern "C" void kernel_launch(void* const* d_in, const int* in_sizes, int n_in,
                              void* d_out, int out_size, void* d_ws, size_t ws_size,
                              hipStream_t stream)
{
  (void)in_sizes; (void)n_in; (void)out_size; (void)ws_size;
  const float* x      = (const float*)d_in[0];
  const float* pos    = (const float*)d_in[1];
  const float* emb_w  = (const float*)d_in[2];
  const float* emb_b  = (const float*)d_in[3];
  const float* edge_w1= (const float*)d_in[4];
  const float* edge_b1= (const float*)d_in[5];
  const float* edge_w2= (const float*)d_in[6];
  const float* edge_b2= (const float*)d_in[7];
  const float* node_w1= (const float*)d_in[8];
  const float* node_b1= (const float*)d_in[9];
  const float* node_w2= (const float*)d_in[10];
  const float* node_b2= (const float*)d_in[11];
  const float* qkv_w  = (const float*)d_in[12];
  const float* qkv_b  = (const float*)d_in[13];
  const float* out_w  = (const float*)d_in[14];
  const float* out_b  = (const float*)d_in[15];
  const float* ln1_g  = (const float*)d_in[16];
  const float* ln1_b  = (const float*)d_in[17];
  const float* ln2_g  = (const float*)d_in[18];
  const float* ln2_b  = (const float*)d_in[19];
  const float* ff_w1  = (const float*)d_in[20];
  const float* ff_b1  = (const float*)d_in[21];
  const float* ff_w2  = (const float*)d_in[22];
  const float* ff_b2  = (const float*)d_in[23];
  const float* cls_w1 = (const float*)d_in[24];
  const float* cls_b1 = (const float*)d_in[25];
  const float* cls_w2 = (const float*)d_in[26];
  const float* cls_b2 = (const float*)d_in[27];
  const int* ei       = (const int*)d_in[28];
  const int* batch    = (const int*)d_in[29];
  float* out = (float*)d_out;

  uint8_t* wp = (uint8_t*)d_ws;
  auto take = [&](size_t nb)->void*{ void* r = wp; wp += (nb + 255) & ~(size_t)255; return r; };
  float* h      = (float*)take((size_t)NN*HH*4);
  bf16*  P      = (bf16*) take((size_t)NN*256*2);
  float* aggr   = (float*)take((size_t)NN*HH*4);
  int*   cnt    = (int*)  take((size_t)NN*4);
  int*   cursor = (int*)  take((size_t)NN*4);
  int*   parts  = (int*)  take((size_t)64*4);
  int4*  rec    = (int4*) take((size_t)EE*16);
  bf16*  wcatT  = (bf16*) take((size_t)3*256*128*2);
  bf16*  w2T    = (bf16*) take((size_t)3*128*128*2);
  bf16*  nw1T   = (bf16*) take((size_t)3*128*256*2);
  bf16*  nw2T   = (bf16*) take((size_t)3*128*128*2);
  float* bcat   = (float*)take((size_t)3*256*4);
  float* gbuf   = (float*)take((size_t)GG*HH*4);
  float* qkvb   = (float*)take((size_t)GG*384*4);
  float* qkvb2  = (float*)take((size_t)GG*384*4);

  dim3 b256(256);
  k_prep<<<dim3(1937), b256, 0, stream>>>(edge_w1, edge_w2, node_w1, node_w2,
    edge_b1, x, emb_w, emb_b, wcatT, w2T, nw1T, nw2T, bcat, h, cnt);
  k_hist<<<dim3(EE/256), b256, 0, stream>>>(ei + EE, cnt);
  k_scanA<<<dim3(10), dim3(1024), 0, stream>>>(cnt, cursor, parts, NN);
  k_scatter<<<dim3(EE/256), b256, 0, stream>>>(ei, pos, cursor, parts, rec);

  k_pgen<<<dim3(625), b256, 0, stream>>>(h, wcatT, bcat, P, aggr);

  for (int l=0;l<3;++l){
    k_edge<<<dim3(EE/128), dim3(512), 0, stream>>>(P, w2T + (size_t)l*16384,
      edge_w1 + ((size_t)l*257 + 256)*128, edge_b2 + (size_t)l*128, rec, aggr);
    if (l < 2){
      k_node<true><<<dim3(625), dim3(512), 0, stream>>>(h, aggr,
        nw1T + (size_t)l*32768, nw2T + (size_t)l*16384, wcatT + (size_t)(l+1)*32768,
        node_b1 + (size_t)l*128, node_b2 + (size_t)l*128, bcat + (size_t)(l+1)*256, P);
    } else {
      k_node<false><<<dim3(625), dim3(512), 0, stream>>>(h, aggr,
        nw1T + (size_t)l*32768, nw2T + (size_t)l*16384, wcatT,
        node_b1 + (size_t)l*128, node_b2 + (size_t)l*128, bcat, P);
    }
  }

  k_pool_qkv<<<dim3(GG), dim3(384), 0, stream>>>(h, batch, qkv_w, qkv_b, gbuf, qkvb);
  k_tail<0><<<dim3(GG), dim3(128), 0, stream>>>(qkvb, out_w, out_b,
    ln1_g, ln1_b, ff_w1, ff_b1, ff_w2, ff_b2, ln2_g, ln2_b, gbuf,
    qkv_w + (size_t)128*384, qkv_b + 384, qkvb2,
    nullptr, nullptr, nullptr, nullptr, nullptr);
  k_tail<1><<<dim3(GG), dim3(128), 0, stream>>>(qkvb2, out_w + (size_t)128*128, out_b + 128,
    ln1_g + 128, ln1_b + 128, ff_w1 + (size_t)128*256, ff_b1 + 256,
    ff_w2 + (size_t)256*128, ff_b2 + 128, ln2_g + 128, ln2_b + 128, gbuf,
    nullptr, nullptr, nullptr,
    cls_w1, cls_b1, cls_w2, cls_b2, out);
}